// Round 13
// baseline (1159.685 us; speedup 1.0000x reference)
//
#include <hip/hip_runtime.h>

// PNLM: patch (15x15) non-local attention + projection + residual.
// k_w    : bf16 weight copies (wqb/wkb zero-padded [160][256], wpb[256][256]).
// k_xb   : x (raster fp32) -> xbb[blk][c][240] bf16 (proven).
// k_fused: NO qkws round-trip. Phase A: weights direct from L2 (bf16), Q
//          scatter-written to LDS (ql), K held in regs then written to the
//          same LDS region (kl) after qf extraction. Phase B: P1 att^T from
//          kl + register qf, softmax, PV from xbb, P4 proj from wpb, residual.
// k_qk / k_attn_s: small-ws fallback (R6-exact, proven, uses qkws).
// NO v_cvt_pk_bf16_f32 inline asm (convicted of NaN R2/R3/R5).

typedef __bf16 bf16x8 __attribute__((ext_vector_type(8)));
typedef float  f32x4  __attribute__((ext_vector_type(4)));

#define MFMA(a,b,c) __builtin_amdgcn_mfma_f32_16x16x32_bf16((a),(b),(c),0,0,0)

#define QK_ROW 320            // fallback path only
#define KL_STRIDE 168         // ql/kl row stride in ushorts (336B, 16B-aligned)
#define XBB_ROW 240           // xbb row length in ushorts (480B)

__device__ __forceinline__ unsigned short f2bf(float f){
  union { float f; unsigned int u; } v; v.f = f;
  unsigned int r = v.u + 0x7FFFu + ((v.u >> 16) & 1u);   // RNE
  return (unsigned short)(r >> 16);
}
__device__ __forceinline__ float bf2f(unsigned short u){
  union { unsigned int u; float f; } v; v.u = ((unsigned int)u) << 16;
  return v.f;
}
__device__ __forceinline__ int swz(int row, int col){
  return row*256 + ((((col >> 3) ^ (row & 7)) << 3) | (col & 7));
}
__device__ __forceinline__ int swzC(int row, int col){
  return row*256 + (col ^ ((((row >> 3) ^ row) & 7) << 3));
}
__device__ __forceinline__ bf16x8 ld_frag_lds(const unsigned short* p, int idx){
  uint4 v = *(const uint4*)(p + idx);
  return __builtin_bit_cast(bf16x8, v);
}
__device__ __forceinline__ bf16x8 ld_frag_b(const void* p){
  uint4 v = *(const uint4*)(p);
  return __builtin_bit_cast(bf16x8, v);
}

__device__ __forceinline__ void repack_frag(const unsigned int* plo, const unsigned int* phi,
                                            uint4* outf, int lane){
  const int nn = lane & 15, hh = lane >> 4;
  const int sla = nn + 32*(hh & 1);
  const int slb = sla + 16;
  const bool up = hh >= 2;
  #pragma unroll
  for (int k = 0; k < 8; ++k){
    unsigned int a0 = (unsigned int)__shfl((int)plo[2*k],   sla);
    unsigned int a1 = (unsigned int)__shfl((int)plo[2*k+1], sla);
    unsigned int b0 = (unsigned int)__shfl((int)phi[2*k],   sla);
    unsigned int b1 = (unsigned int)__shfl((int)phi[2*k+1], sla);
    unsigned int c0 = (unsigned int)__shfl((int)plo[2*k],   slb);
    unsigned int c1 = (unsigned int)__shfl((int)plo[2*k+1], slb);
    unsigned int d0 = (unsigned int)__shfl((int)phi[2*k],   slb);
    unsigned int d1 = (unsigned int)__shfl((int)phi[2*k+1], slb);
    outf[k] = make_uint4(up?a1:a0, up?b1:b0, up?c1:c0, up?d1:d0);
  }
}

// ---------------- kernel W: bf16 weight copies -------------------------------
__global__ __launch_bounds__(256) void k_w(
    const float* __restrict__ wq, const float* __restrict__ wk,
    const float* __restrict__ wproj,
    unsigned short* __restrict__ wqb, unsigned short* __restrict__ wkb,
    unsigned short* __restrict__ wpb)
{
  int i = blockIdx.x*256 + threadIdx.x;             // pair index, grid 288
  if (i < 20480){
    int e = i >> 7, c = (i & 127)*2;
    unsigned int v = 0;
    if (e < 144) v = (unsigned int)f2bf(wq[e*256+c]) | ((unsigned int)f2bf(wq[e*256+c+1]) << 16);
    *(unsigned int*)(wqb + (size_t)i*2) = v;
  } else if (i < 40960){
    int j = i - 20480;
    int e = j >> 7, c = (j & 127)*2;
    unsigned int v = 0;
    if (e < 144) v = (unsigned int)f2bf(wk[e*256+c]) | ((unsigned int)f2bf(wk[e*256+c+1]) << 16);
    *(unsigned int*)(wkb + (size_t)j*2) = v;
  } else if (i < 73728){
    int l = i - 40960;
    int o = l >> 7, c = (l & 127)*2;
    *(unsigned int*)(wpb + (size_t)l*2) =
        (unsigned int)f2bf(wproj[o*256+c]) | ((unsigned int)f2bf(wproj[o*256+c+1]) << 16);
  }
}

// ---------------- kernel 0: x -> xbb blocked transpose (frozen) --------------
__global__ __launch_bounds__(256) void k_xb(
    const float* __restrict__ x, unsigned short* __restrict__ xbb)
{
  __shared__ unsigned short xs[8*15*240];
  const int wg = blockIdx.x;                // b(8) x th(16) x cg(32)
  const int cg = wg & 31;
  const int th = (wg >> 5) & 15;
  const int b  = wg >> 9;
  const int tid = threadIdx.x;

  const float* xb = x + ((size_t)b*256 + cg*8)*57600 + th*15*240;
  for (int i = tid; i < 8*15*120; i += 256){
    int c = i / 1800;
    int rem = i - c*1800;
    int r = rem / 120, p2 = rem - r*120;
    float2 v = *(const float2*)(xb + (size_t)c*57600 + r*240 + p2*2);
    *(unsigned int*)(&xs[(c*15 + r)*240 + p2*2]) =
        (unsigned int)f2bf(v.x) | ((unsigned int)f2bf(v.y) << 16);
  }
  __syncthreads();

  for (int i = tid; i < 8*16*30; i += 256){
    int c = i / 480;
    int rem = i - c*480;
    int tw = rem / 30, ch = rem - tw*30;
    union { unsigned short u16[8]; uint4 u4; } pk;
    #pragma unroll
    for (int j = 0; j < 8; ++j){
      int m = ch*8 + j;
      int r = m / 15, s = m - r*15;
      pk.u16[j] = (m <= 224) ? xs[(c*15 + r)*240 + tw*15 + s] : (unsigned short)0;
    }
    *(uint4*)(xbb + ((size_t)(b*256 + th*16 + tw)*256 + cg*8 + c)*XBB_ROW + ch*8) = pk.u4;
  }
}

// ---------------- fused kernel: projection + attention, no qkws --------------
__global__ __launch_bounds__(512,4) void k_fused(
    const unsigned short* __restrict__ xbb,
    const unsigned short* __restrict__ wqb, const unsigned short* __restrict__ wkb,
    const unsigned short* __restrict__ wpb,
    float* __restrict__ out)
{
  // LDS (81,600B -> 2 WG/CU):
  //   A1: xt[128][256] swzC (0..32,768 ush)
  //   A2: ql[240][168]      (0..40,320)  Q bounce (written during eg loop)
  //   A3: kl[240][168]      (0..40,320)  K (after qf extraction)
  //   B : xl[128][256] (0..32,768) | wl[64][256] (0..16,384 after xl dead)
  //   hwp LUT: 40,320..40,800 (survives everything)
  __shared__ __align__(16) unsigned short S[40800];
  unsigned short* xt = S;
  unsigned short* ql = S;
  unsigned short* kl = S;
  unsigned short* xl = S;
  unsigned short* wl = S;
  unsigned int*  hwp = (unsigned int*)(S + 40320);
  const int wg = blockIdx.x;
  const int b  = wg >> 8;
  const int th = (wg >> 4) & 15, tw = wg & 15;
  const int h0 = th*15, w0 = tw*15;
  const int tid = threadIdx.x;
  const int lane = tid & 63, wave = tid >> 6;
  const int col  = lane & 15, hi = lane >> 4;
  const size_t obase = (size_t)b * 256 * 57600;
  const unsigned short* xbw = xbb + (size_t)wg * (256*XBB_ROW);

  if (tid < 240){
    int ms = tid <= 224 ? tid : 224;
    hwp[tid] = (unsigned int)((h0 + ms/15)*240 + w0 + ms%15);
  }

  // ======== phase A: stage X^T halves, extract af[2][8] ========
  bf16x8 af[2][8];
  #pragma unroll 1
  for (int half = 0; half < 2; ++half){
    if (half) __syncthreads();               // af[0] reads done
    for (int i = tid; i < 256*16; i += 512){
      int c = i >> 4, m8 = i & 15;
      int m = half*128 + m8*8;
      uint4 v = make_uint4(0u,0u,0u,0u);     // rows >= 240: zeros (NaN-safe)
      if (m + 8 <= 240)
        v = *(const uint4*)(xbw + (size_t)c*XBB_ROW + m);
      const unsigned short* pv = (const unsigned short*)&v;
      #pragma unroll
      for (int j = 0; j < 8; ++j)
        xt[swzC(m8*8 + j, c)] = pv[j];
    }
    __syncthreads();
    const int rloc = wave*16 + col;
    if (half == 0){
      #pragma unroll
      for (int k = 0; k < 8; ++k)
        af[0][k] = ld_frag_lds(xt, swzC(rloc, k*32 + hi*8));
    } else {
      #pragma unroll
      for (int k = 0; k < 8; ++k)
        af[1][k] = ld_frag_lds(xt, swzC(rloc, k*32 + hi*8));
    }
  }
  __syncthreads();                           // xt dead -> ql writable

  // ======== eg loop: weights direct from L2, Q -> ql LDS, K -> regs ========
  unsigned int Klo[2][5][2], Khi[2][5][2];
  #pragma unroll
  for (int eg = 0; eg < 5; ++eg){
    #pragma unroll
    for (int et = 0; et < 2; ++et){
      const int ebase = eg*32 + et*16 + col;
      const unsigned short* wqr = wqb + (size_t)ebase*256 + hi*8;
      const unsigned short* wkr = wkb + (size_t)ebase*256 + hi*8;
      f32x4 aq0 = {0.f,0.f,0.f,0.f}, ak0 = {0.f,0.f,0.f,0.f};
      f32x4 aq1 = {0.f,0.f,0.f,0.f}, ak1 = {0.f,0.f,0.f,0.f};
      #pragma unroll
      for (int k = 0; k < 8; ++k){
        bf16x8 bq = ld_frag_b(wqr + k*32);
        bf16x8 bk = ld_frag_b(wkr + k*32);
        aq0 = MFMA(af[0][k], bq, aq0);
        ak0 = MFMA(af[0][k], bk, ak0);
        aq1 = MFMA(af[1][k], bq, aq1);
        ak1 = MFMA(af[1][k], bk, ak1);
      }
      { // Q scatter to ql (rows t*16 + hi*4 + jj)
        const int r0 = (wave*16 + hi*4)*KL_STRIDE + ebase;
        ql[r0                ] = f2bf(aq0[0]);
        ql[r0 +   KL_STRIDE  ] = f2bf(aq0[1]);
        ql[r0 + 2*KL_STRIDE  ] = f2bf(aq0[2]);
        ql[r0 + 3*KL_STRIDE  ] = f2bf(aq0[3]);
        if (wave < 7){
          const int r1 = ((8+wave)*16 + hi*4)*KL_STRIDE + ebase;
          ql[r1               ] = f2bf(aq1[0]);
          ql[r1 +   KL_STRIDE ] = f2bf(aq1[1]);
          ql[r1 + 2*KL_STRIDE ] = f2bf(aq1[2]);
          ql[r1 + 3*KL_STRIDE ] = f2bf(aq1[3]);
        }
      }
      Klo[0][eg][et] = (unsigned int)f2bf(ak0[0]) | ((unsigned int)f2bf(ak0[1]) << 16);
      Khi[0][eg][et] = (unsigned int)f2bf(ak0[2]) | ((unsigned int)f2bf(ak0[3]) << 16);
      Klo[1][eg][et] = (unsigned int)f2bf(ak1[0]) | ((unsigned int)f2bf(ak1[1]) << 16);
      Khi[1][eg][et] = (unsigned int)f2bf(ak1[2]) | ((unsigned int)f2bf(ak1[3]) << 16);
    }
  }
  __syncthreads();                           // all Q written

  // ======== extract qf fragments (both slots) ========
  uint4 qf[2][5];
  #pragma unroll
  for (int slot = 0; slot < 2; ++slot){
    const int nt = wave + slot*8;
    if (nt < 15){
      const int n  = nt*16 + col;
      const int na = n <= 224 ? n : 224;
      #pragma unroll
      for (int c = 0; c < 5; ++c)
        qf[slot][c] = *(const uint4*)(ql + na*KL_STRIDE + c*32 + hi*8);
    }
  }
  __syncthreads();                           // qf reads done -> kl writable

  // ======== write K to kl ========
  #pragma unroll
  for (int eg = 0; eg < 5; ++eg){
    #pragma unroll
    for (int et = 0; et < 2; ++et){
      const int ebase = eg*32 + et*16 + col;
      const int r0 = (wave*16 + hi*4)*KL_STRIDE + ebase;
      kl[r0                ] = (unsigned short)(Klo[0][eg][et] & 0xFFFFu);
      kl[r0 +   KL_STRIDE  ] = (unsigned short)(Klo[0][eg][et] >> 16);
      kl[r0 + 2*KL_STRIDE  ] = (unsigned short)(Khi[0][eg][et] & 0xFFFFu);
      kl[r0 + 3*KL_STRIDE  ] = (unsigned short)(Khi[0][eg][et] >> 16);
      if (wave < 7){
        const int r1 = ((8+wave)*16 + hi*4)*KL_STRIDE + ebase;
        kl[r1               ] = (unsigned short)(Klo[1][eg][et] & 0xFFFFu);
        kl[r1 +   KL_STRIDE ] = (unsigned short)(Klo[1][eg][et] >> 16);
        kl[r1 + 2*KL_STRIDE ] = (unsigned short)(Khi[1][eg][et] & 0xFFFFu);
        kl[r1 + 3*KL_STRIDE ] = (unsigned short)(Khi[1][eg][et] >> 16);
      }
    }
  }
  __syncthreads();                           // kl ready

  // ======== P1: att^T + lane-local softmax + repack ========
  uint4 attf[2][8];
  #pragma unroll
  for (int slot = 0; slot < 2; ++slot){
    const int nt = wave + slot*8;
    if (nt < 15){
      f32x4 at[15];
      #pragma unroll
      for (int T = 0; T < 15; ++T){
        f32x4 acc = {0.f,0.f,0.f,0.f};
        #pragma unroll
        for (int c = 0; c < 5; ++c){
          bf16x8 kf = ld_frag_lds(kl, (T*16 + col)*KL_STRIDE + c*32 + hi*8);
          acc = MFMA(kf, __builtin_bit_cast(bf16x8, qf[slot][c]), acc);
        }
        at[T] = acc;
      }
      const float sc = 0.12022458674074695f;  // log2(e)/12
      float M = -3.0e38f;
      #pragma unroll
      for (int T = 0; T < 15; ++T){
        #pragma unroll
        for (int jj = 0; jj < 4; ++jj){
          int m = T*16 + hi*4 + jj;
          if (m <= 224) M = fmaxf(M, at[T][jj]*sc);
        }
      }
      M = fmaxf(M, __shfl_xor(M, 16));
      M = fmaxf(M, __shfl_xor(M, 32));
      float Ssum = 0.f;
      #pragma unroll
      for (int T = 0; T < 15; ++T){
        #pragma unroll
        for (int jj = 0; jj < 4; ++jj){
          int m = T*16 + hi*4 + jj;
          float v = (m <= 224) ? exp2f(at[T][jj]*sc - M) : 0.f;
          at[T][jj] = v; Ssum += v;
        }
      }
      Ssum += __shfl_xor(Ssum, 16);
      Ssum += __shfl_xor(Ssum, 32);
      const float inv = 1.0f / Ssum;
      unsigned int plo[16], phi[16];
      #pragma unroll
      for (int T = 0; T < 15; ++T){
        plo[T] = (unsigned int)f2bf(at[T][0]*inv) | ((unsigned int)f2bf(at[T][1]*inv) << 16);
        phi[T] = (unsigned int)f2bf(at[T][2]*inv) | ((unsigned int)f2bf(at[T][3]*inv) << 16);
      }
      plo[15] = 0u; phi[15] = 0u;
      repack_frag(plo, phi, attf[slot], lane);
    }
  }

  // ======== P2/P3: X from xbb into xl; PV partials bf16 ========
  unsigned int ylo[2][16], yhi[2][16];
  #pragma unroll
  for (int half = 0; half < 2; ++half){
    __syncthreads();                         // kl readers / prev PV done
    for (int i = tid; i < 128*32; i += 512){
      int c = i >> 5, m8 = i & 31;
      uint4 v = make_uint4(0u,0u,0u,0u);
      if (m8 < 30)
        v = *(const uint4*)(xbw + (size_t)(half*128 + c)*XBB_ROW + m8*8);
      *(uint4*)(&xl[swz(c, m8*8)]) = v;
    }
    __syncthreads();
    #pragma unroll
    for (int slot = 0; slot < 2; ++slot){
      const int nt = wave + slot*8;
      if (nt < 15){
        #pragma unroll
        for (int ct = 0; ct < 8; ++ct){
          f32x4 acc = {0.f,0.f,0.f,0.f};
          #pragma unroll
          for (int k = 0; k < 8; ++k){
            bf16x8 xf = ld_frag_lds(xl, swz(ct*16 + col, k*32 + hi*8));
            acc = MFMA(xf, __builtin_bit_cast(bf16x8, attf[slot][k]), acc);
          }
          ylo[slot][half*8 + ct] = (unsigned int)f2bf(acc[0]) | ((unsigned int)f2bf(acc[1]) << 16);
          yhi[slot][half*8 + ct] = (unsigned int)f2bf(acc[2]) | ((unsigned int)f2bf(acc[3]) << 16);
        }
      }
    }
  }

  uint4 y1f[2][8];
  #pragma unroll
  for (int slot = 0; slot < 2; ++slot){
    const int nt = wave + slot*8;
    if (nt < 15)
      repack_frag(ylo[slot], yhi[slot], y1f[slot], lane);
  }

  // ======== P4: projection from wpb, 4 rounds x 64 rows + residual ========
  #pragma unroll 1
  for (int oe2 = 0; oe2 < 4; ++oe2){
    __syncthreads();                         // PV readers / prev wl readers done
    for (int i = tid; i < 64*32; i += 512){
      int olr = i >> 5, c8 = (i & 31)*8;
      *(uint4*)(&wl[swz(olr, c8)]) =
          *(const uint4*)(wpb + (size_t)(oe2*64 + olr)*256 + c8);
    }
    __syncthreads();
    #pragma unroll
    for (int ot = 0; ot < 4; ++ot){
      bf16x8 awf[8];
      const int olr = ot*16 + col;
      #pragma unroll
      for (int k = 0; k < 8; ++k)
        awf[k] = ld_frag_lds(wl, swz(olr, k*32 + hi*8));
      #pragma unroll
      for (int slot = 0; slot < 2; ++slot){
        const int nt = wave + slot*8;
        if (nt < 15){
          f32x4 y2 = {0.f,0.f,0.f,0.f};
          #pragma unroll
          for (int k = 0; k < 8; ++k)
            y2 = MFMA(awf[k], __builtin_bit_cast(bf16x8, y1f[slot][k]), y2);
          const int n = nt*16 + col;
          if (n <= 224){
            const size_t pix = hwp[n];
            #pragma unroll
            for (int jj = 0; jj < 4; ++jj){
              int o = oe2*64 + ot*16 + hi*4 + jj;
              float xr = bf2f(xbw[(size_t)o*XBB_ROW + n]);
              out[obase + (size_t)o*57600 + pix] = y2[jj] + xr;
            }
          }
        }
      }
    }
  }
}

// ---------------- small-ws fallback: R6-exact --------------------------------
__global__ __launch_bounds__(512) void k_qk(
    const float* __restrict__ x, const float* __restrict__ wq,
    const float* __restrict__ wk,
    unsigned short* __restrict__ qkws)
{
  __shared__ __align__(16) unsigned short S[32768];
  unsigned short* xt  = S;
  unsigned short* wqs = S;
  unsigned short* wks = S + 8192;
  const int wg  = blockIdx.x;
  const int b   = wg / 450;
  const int hw0 = (wg % 450) * 128;
  const int tid = threadIdx.x;
  const int lane = tid & 63, wave = tid >> 6;
  const int col  = lane & 15, hi = lane >> 4;

  {
    const float* xb = x + (size_t)b * 256 * 57600 + hw0;
    const int hw_l = tid & 127;
    #pragma unroll 4
    for (int i = 0; i < 32; ++i){
      int c = ((tid >> 7) * 32 + i) * 2;
      float f0 = xb[(size_t)c     * 57600 + hw_l];
      float f1 = xb[(size_t)(c+1) * 57600 + hw_l];
      *(unsigned int*)(&xt[swz(hw_l, c)]) =
          (unsigned int)f2bf(f0) | ((unsigned int)f2bf(f1) << 16);
    }
  }
  __syncthreads();

  bf16x8 af[8];
  const int arow = wave*16 + col;
  #pragma unroll
  for (int k = 0; k < 8; ++k)
    af[k] = ld_frag_lds(xt, swz(arow, k*32 + hi*8));

  const size_t orow_base = (size_t)b*57600 + hw0 + wave*16;

  for (int eg = 0; eg < 5; ++eg){
    __syncthreads();
    for (int i = 0; i < 8; ++i){
      int idx = tid + i*512;
      int e_l = idx >> 7, c = (idx & 127) * 2;
      int e = eg*32 + e_l;
      float2 vq = make_float2(0.f,0.f), vk = make_float2(0.f,0.f);
      if (e < 144){
        vq = *(const float2*)(wq + (size_t)e*256 + c);
        vk = *(const float2*)(wk + (size_t)e*256 + c);
      }
      *(unsigned int*)(&wqs[swz(e_l, c)]) =
          (unsigned int)f2bf(vq.x) | ((unsigned int)f2bf(vq.y) << 16);
      *(unsigned int*)(&wks[swz(e_l, c)]) =
          (unsigned int)f2bf(vk.x) | ((unsigned int)f2bf(vk.y) << 16);
    }
    __syncthreads();
    #pragma unroll
    for (int etl = 0; etl < 2; ++etl){
      f32x4 aq = {0.f,0.f,0.f,0.f}, ak = {0.f,0.f,0.f,0.f};
      const int el = etl*16 + col;
      #pragma unroll
      for (int k = 0; k < 8; ++k){
        int idx = swz(el, k*32 + hi*8);
        bf16x8 bq = ld_frag_lds(wqs, idx);
        bf16x8 bk = ld_frag_lds(wks, idx);
        aq = MFMA(af[k], bq, aq);
        ak = MFMA(af[k], bk, ak);
      }
      const int e_out = eg*32 + etl*16 + col;
      #pragma unroll
      for (int jj = 0; jj < 4; ++jj){
        size_t row = orow_base + hi*4 + jj;
        qkws[row*QK_ROW + e_out]       = f2bf(aq[jj]);
        qkws[row*QK_ROW + 160 + e_out] = f2bf(ak[jj]);
      }
    }
  }
}

__global__ __launch_bounds__(512,4) void k_attn_s(
    const float* __restrict__ x, const float* __restrict__ wproj,
    const unsigned short* __restrict__ qkws, float* __restrict__ out)
{
  __shared__ __align__(16) unsigned short S[40320 + 480];
  unsigned short* kl = S;
  unsigned short* xl = S;
  unsigned short* wl = S + 32768;
  unsigned int*  hwp = (unsigned int*)(S + 40320);
  const int wg = blockIdx.x;
  const int b  = wg >> 8;
  const int th = (wg >> 4) & 15, tw = wg & 15;
  const int h0 = th*15, w0 = tw*15;
  const int tid = threadIdx.x;
  const int lane = tid & 63, wave = tid >> 6;
  const int col  = lane & 15, hi = lane >> 4;
  const size_t xbase = (size_t)b * 256 * 57600;
  const unsigned short* qkb = qkws + (size_t)b * 57600 * QK_ROW;

  if (tid < 240){
    int ms = tid <= 224 ? tid : 224;
    hwp[tid] = (unsigned int)((h0 + ms/15)*240 + w0 + ms%15);
  }
  __syncthreads();

  for (int i = tid; i < 240*20; i += 512){
    int m = i / 20, eb = i - m*20;
    *(uint4*)(&kl[m*KL_STRIDE + eb*8]) =
        *(const uint4*)(qkb + (size_t)hwp[m]*QK_ROW + 160 + eb*8);
  }
  __syncthreads();

  uint4 attf[2][8];
  #pragma unroll
  for (int slot = 0; slot < 2; ++slot){
    const int nt = wave + slot*8;
    if (nt < 15){
      const int n  = nt*16 + col;
      const int na = n <= 224 ? n : 224;
      const unsigned short* qrow = qkb + (size_t)hwp[na]*QK_ROW;
      bf16x8 qf[5];
      #pragma unroll
      for (int c = 0; c < 5; ++c)
        qf[c] = ld_frag_b(qrow + c*32 + hi*8);
      f32x4 at[15];
      #pragma unroll
      for (int T = 0; T < 15; ++T){
        f32x4 acc = {0.f,0.f,0.f,0.f};
        #pragma unroll
        for (int c = 0; c < 5; ++c){
          bf16x8 kf = ld_frag_lds(kl, (T*16 + col)*KL_STRIDE + c*32 + hi*8);
          acc = MFMA(kf, qf[c], acc);
        }
        at[T] = acc;
      }
      const float sc = 0.12022458674074695f;
      float M = -3.0e38f;
      #pragma unroll
      for (int T = 0; T < 15; ++T){
        #pragma unroll
        for (int jj = 0; jj < 4; ++jj){
          int m = T*16 + hi*4 + jj;
          if (m <= 224) M = fmaxf(M, at[T][jj]*sc);
        }
      }
      M = fmaxf(M, __shfl_xor(M, 16));
      M = fmaxf(M, __shfl_xor(M, 32));
      float Ssum = 0.f;
      #pragma unroll
      for (int T = 0; T < 15; ++T){
        #pragma unroll
        for (int jj = 0; jj < 4; ++jj){
          int m = T*16 + hi*4 + jj;
          float v = (m <= 224) ? exp2f(at[T][jj]*sc - M) : 0.f;
          at[T][jj] = v; Ssum += v;
        }
      }
      Ssum += __shfl_xor(Ssum, 16);
      Ssum += __shfl_xor(Ssum, 32);
      const float inv = 1.0f / Ssum;
      unsigned int plo[16], phi[16];
      #pragma unroll
      for (int T = 0; T < 15; ++T){
        plo[T] = (unsigned int)f2bf(at[T][0]*inv) | ((unsigned int)f2bf(at[T][1]*inv) << 16);
        phi[T] = (unsigned int)f2bf(at[T][2]*inv) | ((unsigned int)f2bf(at[T][3]*inv) << 16);
      }
      plo[15] = 0u; phi[15] = 0u;
      repack_frag(plo, phi, attf[slot], lane);
    }
  }

  unsigned int ylo[2][16], yhi[2][16];
  #pragma unroll
  for (int half = 0; half < 2; ++half){
    __syncthreads();
    for (int i = tid; i < 128*128; i += 512){
      int c = i >> 7, m = (i & 127)*2;
      int m0 = m <= 224 ? m : 224;
      float f0 = (m     <= 224) ? x[xbase + (size_t)(half*128 + c)*57600 + hwp[m0]]   : 0.f;
      float f1 = (m + 1 <= 224) ? x[xbase + (size_t)(half*128 + c)*57600 + hwp[m0+1]] : 0.f;
      *(unsigned int*)(&xl[swz(c, m)]) =
          (unsigned int)f2bf(f0) | ((unsigned int)f2bf(f1) << 16);
    }
    __syncthreads();
    #pragma unroll
    for (int slot = 0; slot < 2; ++slot){
      const int nt = wave + slot*8;
      if (nt < 15){
        #pragma unroll
        for (int ct = 0; ct < 8; ++ct){
          f32x4 acc = {0.f,0.f,0.f,0.f};
          #pragma unroll
          for (int k = 0; k < 8; ++k){
            bf16x8 xf = ld_frag_lds(xl, swz(ct*16 + col, k*32 + hi*8));
            acc = MFMA(xf, __builtin_bit_cast(bf16x8, attf[slot][k]), acc);
          }
          ylo[slot][half*8 + ct] = (unsigned int)f2bf(acc[0]) | ((unsigned int)f2bf(acc[1]) << 16);
          yhi[slot][half*8 + ct] = (unsigned int)f2bf(acc[2]) | ((unsigned int)f2bf(acc[3]) << 16);
        }
      }
    }
  }

  uint4 y1f[2][8];
  #pragma unroll
  for (int slot = 0; slot < 2; ++slot){
    const int nt = wave + slot*8;
    if (nt < 15)
      repack_frag(ylo[slot], yhi[slot], y1f[slot], lane);
  }

  #pragma unroll 1
  for (int oe = 0; oe < 16; ++oe){
    __syncthreads();
    for (int i = tid; i < 16*128; i += 512){
      int olr = i >> 7, c = (i & 127)*2;
      const float* wr = wproj + (size_t)(oe*16 + olr)*256 + c;
      *(unsigned int*)(&wl[swz(olr, c)]) =
          (unsigned int)f2bf(wr[0]) | ((unsigned int)f2bf(wr[1]) << 16);
    }
    __syncthreads();
    bf16x8 awf[8];
    #pragma unroll
    for (int k = 0; k < 8; ++k)
      awf[k] = ld_frag_lds(wl, swz(col, k*32 + hi*8));
    #pragma unroll
    for (int slot = 0; slot < 2; ++slot){
      const int nt = wave + slot*8;
      if (nt < 15){
        f32x4 y2 = {0.f,0.f,0.f,0.f};
        #pragma unroll
        for (int k = 0; k < 8; ++k)
          y2 = MFMA(awf[k], __builtin_bit_cast(bf16x8, y1f[slot][k]), y2);
        const int n = nt*16 + col;
        if (n <= 224){
          const size_t pix = hwp[n];
          #pragma unroll
          for (int jj = 0; jj < 4; ++jj){
            int o = oe*16 + hi*4 + jj;
            const size_t idx = xbase + (size_t)o*57600 + pix;
            out[idx] = y2[jj] + x[idx];
          }
        }
      }
    }
  }
}

extern "C" void kernel_launch(void* const* d_in, const int* in_sizes, int n_in,
                              void* d_out, int out_size, void* d_ws, size_t ws_size,
                              hipStream_t stream)
{
  const float* x     = (const float*)d_in[0];
  const float* wq    = (const float*)d_in[1];
  const float* wk    = (const float*)d_in[2];
  const float* wproj = (const float*)d_in[3];
  float* out = (float*)d_out;
  (void)in_sizes; (void)n_in; (void)out_size;

  const size_t QKWS_B = (size_t)8*57600*QK_ROW*2;        // 294,912,000 (fallback)
  const size_t XBB_B  = (size_t)8*256*256*XBB_ROW*2;     // 251,658,240
  const size_t WB_ALL = (size_t)(160*256 + 160*256 + 256*256)*2;  // 294,912
  unsigned short* qkws = (unsigned short*)d_ws;

  if (ws_size >= XBB_B + WB_ALL){                        // big path: no qkws
    unsigned short* xbb = (unsigned short*)d_ws;
    unsigned short* wqb = (unsigned short*)((char*)d_ws + XBB_B);
    unsigned short* wkb = wqb + 160*256;
    unsigned short* wpb = wkb + 160*256;
    k_w    <<<dim3(288),  dim3(256), 0, stream>>>(wq, wk, wproj, wqb, wkb, wpb);
    k_xb   <<<dim3(4096), dim3(256), 0, stream>>>(x, xbb);
    k_fused<<<dim3(2048), dim3(512), 0, stream>>>(xbb, wqb, wkb, wpb, out);
  } else {
    k_qk    <<<dim3(3600), dim3(512), 0, stream>>>(x, wq, wk, qkws);
    k_attn_s<<<dim3(2048), dim3(512), 0, stream>>>(x, wproj, qkws, out);
  }
}

// Round 15
// 1120.667 us; speedup vs baseline: 1.0348x; 1.0348x over previous
//
#include <hip/hip_runtime.h>

// PNLM: patch (15x15) non-local attention + projection + residual.
// k_w    : bf16 weight copies (wqb/wkb zero-padded [160][256], wpb[256][256]).
// k_xb   : x (raster fp32) -> xbb[blk][c][240] bf16 (proven).
// k_fused: phase A computes Q^T via SWAPPED-OPERAND MFMA (D[e][pixel]) so the
//          proven repack_chunk yields P1's qf B-frags in registers (R14 bug:
//          unswapped D[pixel][e] repacked transposed). K -> kws global,
//          restaged L2-hot into kl. Phase B: att^T, softmax, PV from xbb,
//          P4 proj from wpb (4x64 rounds), bf16 residual.
// k_qk / k_attn_s: small-ws fallback (R6-exact, proven).
// NO v_cvt_pk_bf16_f32 inline asm (NaN, R2/R3/R5).
// NO fragment-granularity global reads (TA-scatter, R4/R13).

typedef __bf16 bf16x8 __attribute__((ext_vector_type(8)));
typedef float  f32x4  __attribute__((ext_vector_type(4)));

#define MFMA(a,b,c) __builtin_amdgcn_mfma_f32_16x16x32_bf16((a),(b),(c),0,0,0)

#define QK_ROW 320            // fallback path only
#define KW_ROW 160            // kws row length (K only), ushorts
#define KL_STRIDE 168         // kl row stride in ushorts (336B, 16B-aligned)
#define XBB_ROW 240           // xbb row length in ushorts (480B)

__device__ __forceinline__ unsigned short f2bf(float f){
  union { float f; unsigned int u; } v; v.f = f;
  unsigned int r = v.u + 0x7FFFu + ((v.u >> 16) & 1u);   // RNE
  return (unsigned short)(r >> 16);
}
__device__ __forceinline__ float bf2f(unsigned short u){
  union { unsigned int u; float f; } v; v.u = ((unsigned int)u) << 16;
  return v.f;
}
__device__ __forceinline__ int swz(int row, int col){
  return row*256 + ((((col >> 3) ^ (row & 7)) << 3) | (col & 7));
}
__device__ __forceinline__ int swzC(int row, int col){
  return row*256 + (col ^ ((((row >> 3) ^ row) & 7) << 3));
}
__device__ __forceinline__ bf16x8 ld_frag_lds(const unsigned short* p, int idx){
  uint4 v = *(const uint4*)(p + idx);
  return __builtin_bit_cast(bf16x8, v);
}
__device__ __forceinline__ bf16x8 ld_frag_b(const void* p){
  uint4 v = *(const uint4*)(p);
  return __builtin_bit_cast(bf16x8, v);
}

// D-layout (rows over 2 tiles -> k, cols -> lane-col) -> operand-frag. Proven.
__device__ __forceinline__ void repack_frag(const unsigned int* plo, const unsigned int* phi,
                                            uint4* outf, int lane){
  const int nn = lane & 15, hh = lane >> 4;
  const int sla = nn + 32*(hh & 1);
  const int slb = sla + 16;
  const bool up = hh >= 2;
  #pragma unroll
  for (int k = 0; k < 8; ++k){
    unsigned int a0 = (unsigned int)__shfl((int)plo[2*k],   sla);
    unsigned int a1 = (unsigned int)__shfl((int)plo[2*k+1], sla);
    unsigned int b0 = (unsigned int)__shfl((int)phi[2*k],   sla);
    unsigned int b1 = (unsigned int)__shfl((int)phi[2*k+1], sla);
    unsigned int c0 = (unsigned int)__shfl((int)plo[2*k],   slb);
    unsigned int c1 = (unsigned int)__shfl((int)plo[2*k+1], slb);
    unsigned int d0 = (unsigned int)__shfl((int)phi[2*k],   slb);
    unsigned int d1 = (unsigned int)__shfl((int)phi[2*k+1], slb);
    outf[k] = make_uint4(up?a1:a0, up?b1:b0, up?c1:c0, up?d1:d0);
  }
}
// Single-chunk version (tiles A=rows 0..15, B=rows 16..31 of the chunk).
__device__ __forceinline__ uint4 repack_chunk(unsigned int ploA, unsigned int phiA,
                                              unsigned int ploB, unsigned int phiB,
                                              int lane){
  const int nn = lane & 15, hh = lane >> 4;
  const int sla = nn + 32*(hh & 1);
  const int slb = sla + 16;
  const bool up = hh >= 2;
  unsigned int a0 = (unsigned int)__shfl((int)ploA, sla);
  unsigned int a1 = (unsigned int)__shfl((int)ploB, sla);
  unsigned int b0 = (unsigned int)__shfl((int)phiA, sla);
  unsigned int b1 = (unsigned int)__shfl((int)phiB, sla);
  unsigned int c0 = (unsigned int)__shfl((int)ploA, slb);
  unsigned int c1 = (unsigned int)__shfl((int)ploB, slb);
  unsigned int d0 = (unsigned int)__shfl((int)phiA, slb);
  unsigned int d1 = (unsigned int)__shfl((int)phiB, slb);
  return make_uint4(up?a1:a0, up?b1:b0, up?c1:c0, up?d1:d0);
}

// ---------------- kernel W: bf16 weight copies -------------------------------
__global__ __launch_bounds__(256) void k_w(
    const float* __restrict__ wq, const float* __restrict__ wk,
    const float* __restrict__ wproj,
    unsigned short* __restrict__ wqb, unsigned short* __restrict__ wkb,
    unsigned short* __restrict__ wpb)
{
  int i = blockIdx.x*256 + threadIdx.x;             // pair index, grid 288
  if (i < 20480){
    int e = i >> 7, c = (i & 127)*2;
    unsigned int v = 0;
    if (e < 144) v = (unsigned int)f2bf(wq[e*256+c]) | ((unsigned int)f2bf(wq[e*256+c+1]) << 16);
    *(unsigned int*)(wqb + (size_t)i*2) = v;
  } else if (i < 40960){
    int j = i - 20480;
    int e = j >> 7, c = (j & 127)*2;
    unsigned int v = 0;
    if (e < 144) v = (unsigned int)f2bf(wk[e*256+c]) | ((unsigned int)f2bf(wk[e*256+c+1]) << 16);
    *(unsigned int*)(wkb + (size_t)j*2) = v;
  } else if (i < 73728){
    int l = i - 40960;
    int o = l >> 7, c = (l & 127)*2;
    *(unsigned int*)(wpb + (size_t)l*2) =
        (unsigned int)f2bf(wproj[o*256+c]) | ((unsigned int)f2bf(wproj[o*256+c+1]) << 16);
  }
}

// ---------------- kernel 0: x -> xbb blocked transpose (frozen) --------------
__global__ __launch_bounds__(256) void k_xb(
    const float* __restrict__ x, unsigned short* __restrict__ xbb)
{
  __shared__ unsigned short xs[8*15*240];
  const int wg = blockIdx.x;                // b(8) x th(16) x cg(32)
  const int cg = wg & 31;
  const int th = (wg >> 5) & 15;
  const int b  = wg >> 9;
  const int tid = threadIdx.x;

  const float* xb = x + ((size_t)b*256 + cg*8)*57600 + th*15*240;
  for (int i = tid; i < 8*15*120; i += 256){
    int c = i / 1800;
    int rem = i - c*1800;
    int r = rem / 120, p2 = rem - r*120;
    float2 v = *(const float2*)(xb + (size_t)c*57600 + r*240 + p2*2);
    *(unsigned int*)(&xs[(c*15 + r)*240 + p2*2]) =
        (unsigned int)f2bf(v.x) | ((unsigned int)f2bf(v.y) << 16);
  }
  __syncthreads();

  for (int i = tid; i < 8*16*30; i += 256){
    int c = i / 480;
    int rem = i - c*480;
    int tw = rem / 30, ch = rem - tw*30;
    union { unsigned short u16[8]; uint4 u4; } pk;
    #pragma unroll
    for (int j = 0; j < 8; ++j){
      int m = ch*8 + j;
      int r = m / 15, s = m - r*15;
      pk.u16[j] = (m <= 224) ? xs[(c*15 + r)*240 + tw*15 + s] : (unsigned short)0;
    }
    *(uint4*)(xbb + ((size_t)(b*256 + th*16 + tw)*256 + cg*8 + c)*XBB_ROW + ch*8) = pk.u4;
  }
}

// ---------------- fused kernel: projection + attention -----------------------
__global__ __launch_bounds__(512,4) void k_fused(
    const unsigned short* __restrict__ xbb,
    const unsigned short* __restrict__ wqb, const unsigned short* __restrict__ wkb,
    const unsigned short* __restrict__ wpb,
    unsigned short* __restrict__ kws, float* __restrict__ out)
{
  // LDS (81,600B -> 2 WG/CU):
  //   A: xt[128][256] swzC (0..32,768 ush); wqs/wks [32][256] alias xt after af.
  //   B: kl[240][168] (0..40,320) | xl[128][256] (0..32,768)
  //      | wl[64][256] (0..16,384 after xl dead) | hwp (40,320..40,800)
  __shared__ __align__(16) unsigned short S[40800];
  unsigned short* xt  = S;
  unsigned short* wqs = S;
  unsigned short* wks = S + 8192;
  unsigned short* kl  = S;
  unsigned short* xl  = S;
  unsigned short* wl  = S;
  unsigned int*  hwp  = (unsigned int*)(S + 40320);
  const int wg = blockIdx.x;
  const int b  = wg >> 8;
  const int th = (wg >> 4) & 15, tw = wg & 15;
  const int h0 = th*15, w0 = tw*15;
  const int tid = threadIdx.x;
  const int lane = tid & 63, wave = tid >> 6;
  const int col  = lane & 15, hi = lane >> 4;
  const size_t obase = (size_t)b * 256 * 57600;
  const unsigned short* kwb = kws + (size_t)b * 57600 * KW_ROW;
  const unsigned short* xbw = xbb + (size_t)wg * (256*XBB_ROW);

  if (tid < 240){
    int ms = tid <= 224 ? tid : 224;
    hwp[tid] = (unsigned int)((h0 + ms/15)*240 + w0 + ms%15);
  }

  // ======== phase A: stage X^T halves, extract af[2][8] ========
  bf16x8 af[2][8];
  #pragma unroll 1
  for (int half = 0; half < 2; ++half){
    if (half) __syncthreads();
    for (int i = tid; i < 256*16; i += 512){
      int c = i >> 4, m8 = i & 15;
      int m = half*128 + m8*8;
      uint4 v = make_uint4(0u,0u,0u,0u);
      if (m + 8 <= 240)
        v = *(const uint4*)(xbw + (size_t)c*XBB_ROW + m);
      const unsigned short* pv = (const unsigned short*)&v;
      #pragma unroll
      for (int j = 0; j < 8; ++j)
        xt[swzC(m8*8 + j, c)] = pv[j];
    }
    __syncthreads();
    const int rloc = wave*16 + col;
    if (half == 0){
      #pragma unroll
      for (int k = 0; k < 8; ++k)
        af[0][k] = ld_frag_lds(xt, swzC(rloc, k*32 + hi*8));
    } else {
      #pragma unroll
      for (int k = 0; k < 8; ++k)
        af[1][k] = ld_frag_lds(xt, swzC(rloc, k*32 + hi*8));
    }
  }
  __syncthreads();                           // xt consumed -> weights region

  // ======== eg loop: LDS weights; Q^T->register frags; K->kws ========
  uint4 qf[2][5];
  #pragma unroll 1
  for (int eg = 0; eg < 5; ++eg){
    if (eg) __syncthreads();                 // prev eg's weight reads done
    for (int i = tid; i < 32*32; i += 512){
      int e_l = i >> 5, c8 = (i & 31)*8;
      size_t off = (size_t)(eg*32 + e_l)*256 + c8;
      *(uint4*)(&wqs[swz(e_l, c8)]) = *(const uint4*)(wqb + off);
      *(uint4*)(&wks[swz(e_l, c8)]) = *(const uint4*)(wkb + off);
    }
    __syncthreads();
    #pragma unroll
    for (int h2 = 0; h2 < 2; ++h2){
      const int t = h2*8 + wave;
      if (t < 15){
        unsigned int plo0=0, phi0=0, plo1=0, phi1=0;
        #pragma unroll
        for (int et = 0; et < 2; ++et){
          f32x4 aqT = {0.f,0.f,0.f,0.f}, ak = {0.f,0.f,0.f,0.f};
          const int el = et*16 + col;
          #pragma unroll
          for (int k = 0; k < 8; ++k){
            int idx = swz(el, k*32 + hi*8);
            bf16x8 wqf = ld_frag_lds(wqs, idx);
            bf16x8 wkf = ld_frag_lds(wks, idx);
            aqT = MFMA(wqf, af[h2][k], aqT);   // D[e][pixel]  (swapped!)
            ak  = MFMA(af[h2][k], wkf, ak);    // D[pixel][e]
          }
          // K store: rows = pixel
          const int e_out = eg*32 + et*16 + col;
          #pragma unroll
          for (int jj = 0; jj < 4; ++jj){
            int m_px = t*16 + hi*4 + jj;
            if (m_px <= 224){
              int hw = (h0 + m_px/15)*240 + w0 + m_px%15;
              kws[((size_t)b*57600 + hw)*KW_ROW + e_out] = f2bf(ak[jj]);
            }
          }
          // Q pack: rows = e (this is what repack_chunk expects)
          unsigned int lo = (unsigned int)f2bf(aqT[0]) | ((unsigned int)f2bf(aqT[1]) << 16);
          unsigned int hi2= (unsigned int)f2bf(aqT[2]) | ((unsigned int)f2bf(aqT[3]) << 16);
          if (et == 0){ plo0 = lo; phi0 = hi2; } else { plo1 = lo; phi1 = hi2; }
        }
        qf[h2][eg] = repack_chunk(plo0, phi0, plo1, phi1, lane);
      }
    }
  }
  __syncthreads();   // drains kws stores

  // ======== phase B: P0 stage K rows into kl (L2-hot) ========
  for (int i = tid; i < 240*20; i += 512){
    int m = i / 20, eb = i - m*20;
    *(uint4*)(&kl[m*KL_STRIDE + eb*8]) =
        *(const uint4*)(kwb + (size_t)hwp[m]*KW_ROW + eb*8);
  }
  __syncthreads();

  // ======== P1: att^T with register qf + lane-local softmax + repack ========
  uint4 attf[2][8];
  #pragma unroll
  for (int slot = 0; slot < 2; ++slot){
    const int nt = wave + slot*8;
    if (nt < 15){
      f32x4 at[15];
      #pragma unroll
      for (int T = 0; T < 15; ++T){
        f32x4 acc = {0.f,0.f,0.f,0.f};
        #pragma unroll
        for (int c = 0; c < 5; ++c){
          bf16x8 kf = ld_frag_lds(kl, (T*16 + col)*KL_STRIDE + c*32 + hi*8);
          acc = MFMA(kf, __builtin_bit_cast(bf16x8, qf[slot][c]), acc);
        }
        at[T] = acc;
      }
      const float sc = 0.12022458674074695f;  // log2(e)/12
      float M = -3.0e38f;
      #pragma unroll
      for (int T = 0; T < 15; ++T){
        #pragma unroll
        for (int jj = 0; jj < 4; ++jj){
          int m = T*16 + hi*4 + jj;
          if (m <= 224) M = fmaxf(M, at[T][jj]*sc);
        }
      }
      M = fmaxf(M, __shfl_xor(M, 16));
      M = fmaxf(M, __shfl_xor(M, 32));
      float Ssum = 0.f;
      #pragma unroll
      for (int T = 0; T < 15; ++T){
        #pragma unroll
        for (int jj = 0; jj < 4; ++jj){
          int m = T*16 + hi*4 + jj;
          float v = (m <= 224) ? exp2f(at[T][jj]*sc - M) : 0.f;
          at[T][jj] = v; Ssum += v;
        }
      }
      Ssum += __shfl_xor(Ssum, 16);
      Ssum += __shfl_xor(Ssum, 32);
      const float inv = 1.0f / Ssum;
      unsigned int plo[16], phi[16];
      #pragma unroll
      for (int T = 0; T < 15; ++T){
        plo[T] = (unsigned int)f2bf(at[T][0]*inv) | ((unsigned int)f2bf(at[T][1]*inv) << 16);
        phi[T] = (unsigned int)f2bf(at[T][2]*inv) | ((unsigned int)f2bf(at[T][3]*inv) << 16);
      }
      plo[15] = 0u; phi[15] = 0u;
      repack_frag(plo, phi, attf[slot], lane);
    }
  }

  // ======== P2/P3: X from xbb into xl; PV partials bf16 ========
  unsigned int ylo[2][16], yhi[2][16];
  #pragma unroll
  for (int half = 0; half < 2; ++half){
    __syncthreads();                         // kl readers / prev PV done
    for (int i = tid; i < 128*32; i += 512){
      int c = i >> 5, m8 = i & 31;
      uint4 v = make_uint4(0u,0u,0u,0u);
      if (m8 < 30)
        v = *(const uint4*)(xbw + (size_t)(half*128 + c)*XBB_ROW + m8*8);
      *(uint4*)(&xl[swz(c, m8*8)]) = v;
    }
    __syncthreads();
    #pragma unroll
    for (int slot = 0; slot < 2; ++slot){
      const int nt = wave + slot*8;
      if (nt < 15){
        #pragma unroll
        for (int ct = 0; ct < 8; ++ct){
          f32x4 acc = {0.f,0.f,0.f,0.f};
          #pragma unroll
          for (int k = 0; k < 8; ++k){
            bf16x8 xf = ld_frag_lds(xl, swz(ct*16 + col, k*32 + hi*8));
            acc = MFMA(xf, __builtin_bit_cast(bf16x8, attf[slot][k]), acc);
          }
          ylo[slot][half*8 + ct] = (unsigned int)f2bf(acc[0]) | ((unsigned int)f2bf(acc[1]) << 16);
          yhi[slot][half*8 + ct] = (unsigned int)f2bf(acc[2]) | ((unsigned int)f2bf(acc[3]) << 16);
        }
      }
    }
  }

  uint4 y1f[2][8];
  #pragma unroll
  for (int slot = 0; slot < 2; ++slot){
    const int nt = wave + slot*8;
    if (nt < 15)
      repack_frag(ylo[slot], yhi[slot], y1f[slot], lane);
  }

  // ======== P4: projection from wpb, 4 rounds x 64 rows + residual ========
  #pragma unroll 1
  for (int oe2 = 0; oe2 < 4; ++oe2){
    __syncthreads();
    for (int i = tid; i < 64*32; i += 512){
      int olr = i >> 5, c8 = (i & 31)*8;
      *(uint4*)(&wl[swz(olr, c8)]) =
          *(const uint4*)(wpb + (size_t)(oe2*64 + olr)*256 + c8);
    }
    __syncthreads();
    #pragma unroll
    for (int ot = 0; ot < 4; ++ot){
      bf16x8 awf[8];
      const int olr = ot*16 + col;
      #pragma unroll
      for (int k = 0; k < 8; ++k)
        awf[k] = ld_frag_lds(wl, swz(olr, k*32 + hi*8));
      #pragma unroll
      for (int slot = 0; slot < 2; ++slot){
        const int nt = wave + slot*8;
        if (nt < 15){
          f32x4 y2 = {0.f,0.f,0.f,0.f};
          #pragma unroll
          for (int k = 0; k < 8; ++k)
            y2 = MFMA(awf[k], __builtin_bit_cast(bf16x8, y1f[slot][k]), y2);
          const int n = nt*16 + col;
          if (n <= 224){
            const size_t pix = hwp[n];
            #pragma unroll
            for (int jj = 0; jj < 4; ++jj){
              int o = oe2*64 + ot*16 + hi*4 + jj;
              float xr = bf2f(xbw[(size_t)o*XBB_ROW + n]);
              out[obase + (size_t)o*57600 + pix] = y2[jj] + xr;
            }
          }
        }
      }
    }
  }
}

// ---------------- small-ws fallback: R6-exact --------------------------------
__global__ __launch_bounds__(512) void k_qk(
    const float* __restrict__ x, const float* __restrict__ wq,
    const float* __restrict__ wk,
    unsigned short* __restrict__ qkws)
{
  __shared__ __align__(16) unsigned short S[32768];
  unsigned short* xt  = S;
  unsigned short* wqs = S;
  unsigned short* wks = S + 8192;
  const int wg  = blockIdx.x;
  const int b   = wg / 450;
  const int hw0 = (wg % 450) * 128;
  const int tid = threadIdx.x;
  const int lane = tid & 63, wave = tid >> 6;
  const int col  = lane & 15, hi = lane >> 4;

  {
    const float* xb = x + (size_t)b * 256 * 57600 + hw0;
    const int hw_l = tid & 127;
    #pragma unroll 4
    for (int i = 0; i < 32; ++i){
      int c = ((tid >> 7) * 32 + i) * 2;
      float f0 = xb[(size_t)c     * 57600 + hw_l];
      float f1 = xb[(size_t)(c+1) * 57600 + hw_l];
      *(unsigned int*)(&xt[swz(hw_l, c)]) =
          (unsigned int)f2bf(f0) | ((unsigned int)f2bf(f1) << 16);
    }
  }
  __syncthreads();

  bf16x8 af[8];
  const int arow = wave*16 + col;
  #pragma unroll
  for (int k = 0; k < 8; ++k)
    af[k] = ld_frag_lds(xt, swz(arow, k*32 + hi*8));

  const size_t orow_base = (size_t)b*57600 + hw0 + wave*16;

  for (int eg = 0; eg < 5; ++eg){
    __syncthreads();
    for (int i = 0; i < 8; ++i){
      int idx = tid + i*512;
      int e_l = idx >> 7, c = (idx & 127) * 2;
      int e = eg*32 + e_l;
      float2 vq = make_float2(0.f,0.f), vk = make_float2(0.f,0.f);
      if (e < 144){
        vq = *(const float2*)(wq + (size_t)e*256 + c);
        vk = *(const float2*)(wk + (size_t)e*256 + c);
      }
      *(unsigned int*)(&wqs[swz(e_l, c)]) =
          (unsigned int)f2bf(vq.x) | ((unsigned int)f2bf(vq.y) << 16);
      *(unsigned int*)(&wks[swz(e_l, c)]) =
          (unsigned int)f2bf(vk.x) | ((unsigned int)f2bf(vk.y) << 16);
    }
    __syncthreads();
    #pragma unroll
    for (int etl = 0; etl < 2; ++etl){
      f32x4 aq = {0.f,0.f,0.f,0.f}, ak = {0.f,0.f,0.f,0.f};
      const int el = etl*16 + col;
      #pragma unroll
      for (int k = 0; k < 8; ++k){
        int idx = swz(el, k*32 + hi*8);
        bf16x8 bq = ld_frag_lds(wqs, idx);
        bf16x8 bk = ld_frag_lds(wks, idx);
        aq = MFMA(af[k], bq, aq);
        ak = MFMA(af[k], bk, ak);
      }
      const int e_out = eg*32 + etl*16 + col;
      #pragma unroll
      for (int jj = 0; jj < 4; ++jj){
        size_t row = orow_base + hi*4 + jj;
        qkws[row*QK_ROW + e_out]       = f2bf(aq[jj]);
        qkws[row*QK_ROW + 160 + e_out] = f2bf(ak[jj]);
      }
    }
  }
}

__global__ __launch_bounds__(512,4) void k_attn_s(
    const float* __restrict__ x, const float* __restrict__ wproj,
    const unsigned short* __restrict__ qkws, float* __restrict__ out)
{
  __shared__ __align__(16) unsigned short S[40320 + 480];
  unsigned short* kl = S;
  unsigned short* xl = S;
  unsigned short* wl = S + 32768;
  unsigned int*  hwp = (unsigned int*)(S + 40320);
  const int wg = blockIdx.x;
  const int b  = wg >> 8;
  const int th = (wg >> 4) & 15, tw = wg & 15;
  const int h0 = th*15, w0 = tw*15;
  const int tid = threadIdx.x;
  const int lane = tid & 63, wave = tid >> 6;
  const int col  = lane & 15, hi = lane >> 4;
  const size_t xbase = (size_t)b * 256 * 57600;
  const unsigned short* qkb = qkws + (size_t)b * 57600 * QK_ROW;

  if (tid < 240){
    int ms = tid <= 224 ? tid : 224;
    hwp[tid] = (unsigned int)((h0 + ms/15)*240 + w0 + ms%15);
  }
  __syncthreads();

  for (int i = tid; i < 240*20; i += 512){
    int m = i / 20, eb = i - m*20;
    *(uint4*)(&kl[m*KL_STRIDE + eb*8]) =
        *(const uint4*)(qkb + (size_t)hwp[m]*QK_ROW + 160 + eb*8);
  }
  __syncthreads();

  uint4 attf[2][8];
  #pragma unroll
  for (int slot = 0; slot < 2; ++slot){
    const int nt = wave + slot*8;
    if (nt < 15){
      const int n  = nt*16 + col;
      const int na = n <= 224 ? n : 224;
      const unsigned short* qrow = qkb + (size_t)hwp[na]*QK_ROW;
      bf16x8 qf[5];
      #pragma unroll
      for (int c = 0; c < 5; ++c)
        qf[c] = ld_frag_b(qrow + c*32 + hi*8);
      f32x4 at[15];
      #pragma unroll
      for (int T = 0; T < 15; ++T){
        f32x4 acc = {0.f,0.f,0.f,0.f};
        #pragma unroll
        for (int c = 0; c < 5; ++c){
          bf16x8 kf = ld_frag_lds(kl, (T*16 + col)*KL_STRIDE + c*32 + hi*8);
          acc = MFMA(kf, qf[c], acc);
        }
        at[T] = acc;
      }
      const float sc = 0.12022458674074695f;
      float M = -3.0e38f;
      #pragma unroll
      for (int T = 0; T < 15; ++T){
        #pragma unroll
        for (int jj = 0; jj < 4; ++jj){
          int m = T*16 + hi*4 + jj;
          if (m <= 224) M = fmaxf(M, at[T][jj]*sc);
        }
      }
      M = fmaxf(M, __shfl_xor(M, 16));
      M = fmaxf(M, __shfl_xor(M, 32));
      float Ssum = 0.f;
      #pragma unroll
      for (int T = 0; T < 15; ++T){
        #pragma unroll
        for (int jj = 0; jj < 4; ++jj){
          int m = T*16 + hi*4 + jj;
          float v = (m <= 224) ? exp2f(at[T][jj]*sc - M) : 0.f;
          at[T][jj] = v; Ssum += v;
        }
      }
      Ssum += __shfl_xor(Ssum, 16);
      Ssum += __shfl_xor(Ssum, 32);
      const float inv = 1.0f / Ssum;
      unsigned int plo[16], phi[16];
      #pragma unroll
      for (int T = 0; T < 15; ++T){
        plo[T] = (unsigned int)f2bf(at[T][0]*inv) | ((unsigned int)f2bf(at[T][1]*inv) << 16);
        phi[T] = (unsigned int)f2bf(at[T][2]*inv) | ((unsigned int)f2bf(at[T][3]*inv) << 16);
      }
      plo[15] = 0u; phi[15] = 0u;
      repack_frag(plo, phi, attf[slot], lane);
    }
  }

  unsigned int ylo[2][16], yhi[2][16];
  #pragma unroll
  for (int half = 0; half < 2; ++half){
    __syncthreads();
    for (int i = tid; i < 128*128; i += 512){
      int c = i >> 7, m = (i & 127)*2;
      int m0 = m <= 224 ? m : 224;
      float f0 = (m     <= 224) ? x[xbase + (size_t)(half*128 + c)*57600 + hwp[m0]]   : 0.f;
      float f1 = (m + 1 <= 224) ? x[xbase + (size_t)(half*128 + c)*57600 + hwp[m0+1]] : 0.f;
      *(unsigned int*)(&xl[swz(c, m)]) =
          (unsigned int)f2bf(f0) | ((unsigned int)f2bf(f1) << 16);
    }
    __syncthreads();
    #pragma unroll
    for (int slot = 0; slot < 2; ++slot){
      const int nt = wave + slot*8;
      if (nt < 15){
        #pragma unroll
        for (int ct = 0; ct < 8; ++ct){
          f32x4 acc = {0.f,0.f,0.f,0.f};
          #pragma unroll
          for (int k = 0; k < 8; ++k){
            bf16x8 xf = ld_frag_lds(xl, swz(ct*16 + col, k*32 + hi*8));
            acc = MFMA(xf, __builtin_bit_cast(bf16x8, attf[slot][k]), acc);
          }
          ylo[slot][half*8 + ct] = (unsigned int)f2bf(acc[0]) | ((unsigned int)f2bf(acc[1]) << 16);
          yhi[slot][half*8 + ct] = (unsigned int)f2bf(acc[2]) | ((unsigned int)f2bf(acc[3]) << 16);
        }
      }
    }
  }

  uint4 y1f[2][8];
  #pragma unroll
  for (int slot = 0; slot < 2; ++slot){
    const int nt = wave + slot*8;
    if (nt < 15)
      repack_frag(ylo[slot], yhi[slot], y1f[slot], lane);
  }

  #pragma unroll 1
  for (int oe = 0; oe < 16; ++oe){
    __syncthreads();
    for (int i = tid; i < 16*128; i += 512){
      int olr = i >> 7, c = (i & 127)*2;
      const float* wr = wproj + (size_t)(oe*16 + olr)*256 + c;
      *(unsigned int*)(&wl[swz(olr, c)]) =
          (unsigned int)f2bf(wr[0]) | ((unsigned int)f2bf(wr[1]) << 16);
    }
    __syncthreads();
    bf16x8 awf[8];
    #pragma unroll
    for (int k = 0; k < 8; ++k)
      awf[k] = ld_frag_lds(wl, swz(col, k*32 + hi*8));
    #pragma unroll
    for (int slot = 0; slot < 2; ++slot){
      const int nt = wave + slot*8;
      if (nt < 15){
        f32x4 y2 = {0.f,0.f,0.f,0.f};
        #pragma unroll
        for (int k = 0; k < 8; ++k)
          y2 = MFMA(awf[k], __builtin_bit_cast(bf16x8, y1f[slot][k]), y2);
        const int n = nt*16 + col;
        if (n <= 224){
          const size_t pix = hwp[n];
          #pragma unroll
          for (int jj = 0; jj < 4; ++jj){
            int o = oe*16 + hi*4 + jj;
            const size_t idx = xbase + (size_t)o*57600 + pix;
            out[idx] = y2[jj] + x[idx];
          }
        }
      }
    }
  }
}

extern "C" void kernel_launch(void* const* d_in, const int* in_sizes, int n_in,
                              void* d_out, int out_size, void* d_ws, size_t ws_size,
                              hipStream_t stream)
{
  const float* x     = (const float*)d_in[0];
  const float* wq    = (const float*)d_in[1];
  const float* wk    = (const float*)d_in[2];
  const float* wproj = (const float*)d_in[3];
  float* out = (float*)d_out;
  (void)in_sizes; (void)n_in; (void)out_size;

  const size_t QKWS_B = (size_t)8*57600*QK_ROW*2;        // 294,912,000 (fallback)
  const size_t XBB_B  = (size_t)8*256*256*XBB_ROW*2;     // 251,658,240
  const size_t WB_ALL = (size_t)(160*256 + 160*256 + 256*256)*2;  // 294,912
  const size_t KWS_B  = (size_t)8*57600*KW_ROW*2;        // 147,456,000

  if (ws_size >= XBB_B + WB_ALL + KWS_B){                // 399.4 MB (fits; R10)
    unsigned short* xbb = (unsigned short*)d_ws;
    unsigned short* wqb = (unsigned short*)((char*)d_ws + XBB_B);
    unsigned short* wkb = wqb + 160*256;
    unsigned short* wpb = wkb + 160*256;
    unsigned short* kws = (unsigned short*)((char*)d_ws + XBB_B + WB_ALL);
    k_w    <<<dim3(288),  dim3(256), 0, stream>>>(wq, wk, wproj, wqb, wkb, wpb);
    k_xb   <<<dim3(4096), dim3(256), 0, stream>>>(x, xbb);
    k_fused<<<dim3(2048), dim3(512), 0, stream>>>(xbb, wqb, wkb, wpb, kws, out);
  } else {
    unsigned short* qkws = (unsigned short*)d_ws;
    k_qk    <<<dim3(3600), dim3(512), 0, stream>>>(x, wq, wk, qkws);
    k_attn_s<<<dim3(2048), dim3(512), 0, stream>>>(x, wproj, qkws, out);
  }
}

// Round 16
// 968.588 us; speedup vs baseline: 1.1973x; 1.1570x over previous
//
#include <hip/hip_runtime.h>

// PNLM: patch (15x15) non-local attention + projection + residual.
// k_w    : bf16 weight copies (wqb/wkb zero-padded [160][256], wpb[256][256]).
// k_xb   : x (raster fp32) -> xbb[blk][c][240] bf16 (proven).
// k_fused: R12-proven structure (best: 946 total). ONE change: phase A's Q/K
//          results bounce through LDS qb[225][64] per eg, then coalesced 64B-run
//          copies into qkws (replaces 2B scattered stores, kills RMW
//          amplification). Identical stored bytes -> absmax unchanged.
// k_qk / k_attn_s: small-ws fallback (R6-exact, proven).
// NO v_cvt_pk_bf16_f32 inline asm (NaN, R2/R3/R5).
// NO fragment-granularity global reads (TA-scatter, R4/R13).
// NO large register sets held across phase A (spills, R8/R15).

typedef __bf16 bf16x8 __attribute__((ext_vector_type(8)));
typedef float  f32x4  __attribute__((ext_vector_type(4)));

#define MFMA(a,b,c) __builtin_amdgcn_mfma_f32_16x16x32_bf16((a),(b),(c),0,0,0)

#define QK_ROW 320            // Q cols 0..159 (144+ zero), K cols 160..319 (144+ zero)
#define KL_STRIDE 168         // kl row stride in ushorts (336B, 16B-aligned)
#define XBB_ROW 240           // xbb row length in ushorts (480B)

__device__ __forceinline__ unsigned short f2bf(float f){
  union { float f; unsigned int u; } v; v.f = f;
  unsigned int r = v.u + 0x7FFFu + ((v.u >> 16) & 1u);   // RNE
  return (unsigned short)(r >> 16);
}
__device__ __forceinline__ float bf2f(unsigned short u){
  union { unsigned int u; float f; } v; v.u = ((unsigned int)u) << 16;
  return v.f;
}
__device__ __forceinline__ int swz(int row, int col){
  return row*256 + ((((col >> 3) ^ (row & 7)) << 3) | (col & 7));
}
__device__ __forceinline__ int swzC(int row, int col){
  return row*256 + (col ^ ((((row >> 3) ^ row) & 7) << 3));
}
__device__ __forceinline__ bf16x8 ld_frag_lds(const unsigned short* p, int idx){
  uint4 v = *(const uint4*)(p + idx);
  return __builtin_bit_cast(bf16x8, v);
}
__device__ __forceinline__ bf16x8 ld_frag_b(const void* p){
  uint4 v = *(const uint4*)(p);
  return __builtin_bit_cast(bf16x8, v);
}

__device__ __forceinline__ void repack_frag(const unsigned int* plo, const unsigned int* phi,
                                            uint4* outf, int lane){
  const int nn = lane & 15, hh = lane >> 4;
  const int sla = nn + 32*(hh & 1);
  const int slb = sla + 16;
  const bool up = hh >= 2;
  #pragma unroll
  for (int k = 0; k < 8; ++k){
    unsigned int a0 = (unsigned int)__shfl((int)plo[2*k],   sla);
    unsigned int a1 = (unsigned int)__shfl((int)plo[2*k+1], sla);
    unsigned int b0 = (unsigned int)__shfl((int)phi[2*k],   sla);
    unsigned int b1 = (unsigned int)__shfl((int)phi[2*k+1], sla);
    unsigned int c0 = (unsigned int)__shfl((int)plo[2*k],   slb);
    unsigned int c1 = (unsigned int)__shfl((int)plo[2*k+1], slb);
    unsigned int d0 = (unsigned int)__shfl((int)phi[2*k],   slb);
    unsigned int d1 = (unsigned int)__shfl((int)phi[2*k+1], slb);
    outf[k] = make_uint4(up?a1:a0, up?b1:b0, up?c1:c0, up?d1:d0);
  }
}

// ---------------- kernel W: bf16 weight copies -------------------------------
__global__ __launch_bounds__(256) void k_w(
    const float* __restrict__ wq, const float* __restrict__ wk,
    const float* __restrict__ wproj,
    unsigned short* __restrict__ wqb, unsigned short* __restrict__ wkb,
    unsigned short* __restrict__ wpb)
{
  int i = blockIdx.x*256 + threadIdx.x;             // pair index, grid 288
  if (i < 20480){
    int e = i >> 7, c = (i & 127)*2;
    unsigned int v = 0;
    if (e < 144) v = (unsigned int)f2bf(wq[e*256+c]) | ((unsigned int)f2bf(wq[e*256+c+1]) << 16);
    *(unsigned int*)(wqb + (size_t)i*2) = v;
  } else if (i < 40960){
    int j = i - 20480;
    int e = j >> 7, c = (j & 127)*2;
    unsigned int v = 0;
    if (e < 144) v = (unsigned int)f2bf(wk[e*256+c]) | ((unsigned int)f2bf(wk[e*256+c+1]) << 16);
    *(unsigned int*)(wkb + (size_t)j*2) = v;
  } else if (i < 73728){
    int l = i - 40960;
    int o = l >> 7, c = (l & 127)*2;
    *(unsigned int*)(wpb + (size_t)l*2) =
        (unsigned int)f2bf(wproj[o*256+c]) | ((unsigned int)f2bf(wproj[o*256+c+1]) << 16);
  }
}

// ---------------- kernel 0: x -> xbb blocked transpose (frozen) --------------
__global__ __launch_bounds__(256) void k_xb(
    const float* __restrict__ x, unsigned short* __restrict__ xbb)
{
  __shared__ unsigned short xs[8*15*240];
  const int wg = blockIdx.x;                // b(8) x th(16) x cg(32)
  const int cg = wg & 31;
  const int th = (wg >> 5) & 15;
  const int b  = wg >> 9;
  const int tid = threadIdx.x;

  const float* xb = x + ((size_t)b*256 + cg*8)*57600 + th*15*240;
  for (int i = tid; i < 8*15*120; i += 256){
    int c = i / 1800;
    int rem = i - c*1800;
    int r = rem / 120, p2 = rem - r*120;
    float2 v = *(const float2*)(xb + (size_t)c*57600 + r*240 + p2*2);
    *(unsigned int*)(&xs[(c*15 + r)*240 + p2*2]) =
        (unsigned int)f2bf(v.x) | ((unsigned int)f2bf(v.y) << 16);
  }
  __syncthreads();

  for (int i = tid; i < 8*16*30; i += 256){
    int c = i / 480;
    int rem = i - c*480;
    int tw = rem / 30, ch = rem - tw*30;
    union { unsigned short u16[8]; uint4 u4; } pk;
    #pragma unroll
    for (int j = 0; j < 8; ++j){
      int m = ch*8 + j;
      int r = m / 15, s = m - r*15;
      pk.u16[j] = (m <= 224) ? xs[(c*15 + r)*240 + tw*15 + s] : (unsigned short)0;
    }
    *(uint4*)(xbb + ((size_t)(b*256 + th*16 + tw)*256 + cg*8 + c)*XBB_ROW + ch*8) = pk.u4;
  }
}

// ---------------- fused kernel: QK projection + attention --------------------
__global__ __launch_bounds__(512,4) void k_fused(
    const unsigned short* __restrict__ xbb,
    const unsigned short* __restrict__ wqb, const unsigned short* __restrict__ wkb,
    const unsigned short* __restrict__ wpb,
    unsigned short* __restrict__ qkws, float* __restrict__ out)
{
  // LDS union (81,920B -> 2 WG/CU):
  //   phase A: xt[128][256] swzC (0..32,768 ush); after af: wqs/wks (0..16,384)
  //            + qb bounce [225][64] (16,384..30,784).
  //   phase B: kl[240][168] (0..40,320) | xl[128][256] (0..32,768)
  //            | wl[64][256] (0..16,384 after xl dead) | hwp (40,320..40,800)
  __shared__ __align__(16) unsigned short S[40960];
  unsigned short* xt  = S;
  unsigned short* wqs = S;
  unsigned short* wks = S + 8192;
  unsigned short* qb  = S + 16384;          // bounce: row m_px (0..224) * 64
  unsigned short* kl  = S;
  unsigned short* xl  = S;
  unsigned short* wl  = S;
  unsigned int*  hwp  = (unsigned int*)(S + 40320);
  const int wg = blockIdx.x;
  const int b  = wg >> 8;
  const int th = (wg >> 4) & 15, tw = wg & 15;
  const int h0 = th*15, w0 = tw*15;
  const int tid = threadIdx.x;
  const int lane = tid & 63, wave = tid >> 6;
  const int col  = lane & 15, hi = lane >> 4;
  const size_t obase = (size_t)b * 256 * 57600;
  const unsigned short* qkb = qkws + (size_t)b * 57600 * QK_ROW;
  const unsigned short* xbw = xbb + (size_t)wg * (256*XBB_ROW);

  if (tid < 240){                               // hwp region untouched by phase A
    int ms = tid <= 224 ? tid : 224;
    hwp[tid] = (unsigned int)((h0 + ms/15)*240 + w0 + ms%15);
  }

  // ================= phase A: QK projection ==================================
  bf16x8 af[2][8];
  #pragma unroll 1
  for (int half = 0; half < 2; ++half){
    if (half) __syncthreads();
    for (int i = tid; i < 256*16; i += 512){
      int c = i >> 4, m8 = i & 15;
      int m = half*128 + m8*8;
      uint4 v = make_uint4(0u,0u,0u,0u);
      if (m + 8 <= 240)
        v = *(const uint4*)(xbw + (size_t)c*XBB_ROW + m);
      const unsigned short* pv = (const unsigned short*)&v;
      #pragma unroll
      for (int j = 0; j < 8; ++j)
        xt[swzC(m8*8 + j, c)] = pv[j];
    }
    __syncthreads();
    const int rloc = wave*16 + col;
    if (half == 0){
      #pragma unroll
      for (int k = 0; k < 8; ++k)
        af[0][k] = ld_frag_lds(xt, swzC(rloc, k*32 + hi*8));
    } else {
      #pragma unroll
      for (int k = 0; k < 8; ++k)
        af[1][k] = ld_frag_lds(xt, swzC(rloc, k*32 + hi*8));
    }
  }
  __syncthreads();                             // xt consumed -> weights + qb

  #pragma unroll 1
  for (int eg = 0; eg < 5; ++eg){
    if (eg) __syncthreads();                   // prev weight reads + qb copy done
    for (int i = tid; i < 32*32; i += 512){
      int e_l = i >> 5, c8 = (i & 31)*8;
      size_t off = (size_t)(eg*32 + e_l)*256 + c8;
      *(uint4*)(&wqs[swz(e_l, c8)]) = *(const uint4*)(wqb + off);
      *(uint4*)(&wks[swz(e_l, c8)]) = *(const uint4*)(wkb + off);
    }
    __syncthreads();
    #pragma unroll
    for (int h2 = 0; h2 < 2; ++h2){
      const int t = h2*8 + wave;
      if (t < 15){
        #pragma unroll
        for (int et = 0; et < 2; ++et){
          f32x4 aq = {0.f,0.f,0.f,0.f}, ak = {0.f,0.f,0.f,0.f};
          const int el = et*16 + col;
          #pragma unroll
          for (int k = 0; k < 8; ++k){
            int idx = swz(el, k*32 + hi*8);
            aq = MFMA(af[h2][k], ld_frag_lds(wqs, idx), aq);
            ak = MFMA(af[h2][k], ld_frag_lds(wks, idx), ak);
          }
          const int ecol = et*16 + col;        // 0..31 within this eg
          #pragma unroll
          for (int jj = 0; jj < 4; ++jj){
            int m_px = t*16 + hi*4 + jj;
            if (m_px <= 224){
              qb[m_px*64 + ecol]      = f2bf(aq[jj]);
              qb[m_px*64 + 32 + ecol] = f2bf(ak[jj]);
            }
          }
        }
      }
    }
    __syncthreads();                           // qb filled
    // coalesced copy: 225 rows x (4 Q + 4 K) 16B chunks -> 64B runs in qkws
    for (int i = tid; i < 225*8; i += 512){
      int row = i >> 3, ch = i & 7;
      const size_t qrow = ((size_t)b*57600 + hwp[row])*QK_ROW;
      uint4 v = *(const uint4*)(qb + row*64 + ch*8);
      size_t dst = (ch < 4) ? qrow + eg*32 + ch*8
                            : qrow + 160 + eg*32 + (ch-4)*8;
      *(uint4*)(qkws + dst) = v;
    }
  }
  __syncthreads();   // phase boundary: drains qkws stores; weights/qb dead

  // ================= phase B: attention ======================================
  // ---- P0: stage K rows into kl (L2-hot reads of own block's rows) ----
  for (int i = tid; i < 240*20; i += 512){
    int m = i / 20, eb = i - m*20;
    *(uint4*)(&kl[m*KL_STRIDE + eb*8]) =
        *(const uint4*)(qkb + (size_t)hwp[m]*QK_ROW + 160 + eb*8);
  }
  __syncthreads();

  // ---- P1: att^T strips + lane-local softmax + register repack ----
  uint4 attf[2][8];
  #pragma unroll
  for (int slot = 0; slot < 2; ++slot){
    const int nt = wave + slot*8;
    if (nt < 15){
      const int n  = nt*16 + col;
      const int na = n <= 224 ? n : 224;
      const unsigned short* qrow = qkb + (size_t)hwp[na]*QK_ROW;
      bf16x8 qf[5];
      #pragma unroll
      for (int c = 0; c < 5; ++c)
        qf[c] = ld_frag_b(qrow + c*32 + hi*8);
      f32x4 at[15];
      #pragma unroll
      for (int T = 0; T < 15; ++T){
        f32x4 acc = {0.f,0.f,0.f,0.f};
        #pragma unroll
        for (int c = 0; c < 5; ++c){
          bf16x8 kf = ld_frag_lds(kl, (T*16 + col)*KL_STRIDE + c*32 + hi*8);
          acc = MFMA(kf, qf[c], acc);             // att^T[m][n]
        }
        at[T] = acc;
      }
      const float sc = 0.12022458674074695f;      // log2(e)/12
      float M = -3.0e38f;
      #pragma unroll
      for (int T = 0; T < 15; ++T){
        #pragma unroll
        for (int jj = 0; jj < 4; ++jj){
          int m = T*16 + hi*4 + jj;
          if (m <= 224) M = fmaxf(M, at[T][jj]*sc);
        }
      }
      M = fmaxf(M, __shfl_xor(M, 16));
      M = fmaxf(M, __shfl_xor(M, 32));
      float Ssum = 0.f;
      #pragma unroll
      for (int T = 0; T < 15; ++T){
        #pragma unroll
        for (int jj = 0; jj < 4; ++jj){
          int m = T*16 + hi*4 + jj;
          float v = (m <= 224) ? exp2f(at[T][jj]*sc - M) : 0.f;
          at[T][jj] = v; Ssum += v;
        }
      }
      Ssum += __shfl_xor(Ssum, 16);
      Ssum += __shfl_xor(Ssum, 32);
      const float inv = 1.0f / Ssum;
      unsigned int plo[16], phi[16];
      #pragma unroll
      for (int T = 0; T < 15; ++T){
        plo[T] = (unsigned int)f2bf(at[T][0]*inv) | ((unsigned int)f2bf(at[T][1]*inv) << 16);
        phi[T] = (unsigned int)f2bf(at[T][2]*inv) | ((unsigned int)f2bf(at[T][3]*inv) << 16);
      }
      plo[15] = 0u; phi[15] = 0u;
      repack_frag(plo, phi, attf[slot], lane);
    }
  }

  // hoist per-slot store coords
  int pixs[2];
  #pragma unroll
  for (int slot = 0; slot < 2; ++slot){
    const int n = (wave + slot*8)*16 + col;
    pixs[slot] = (n <= 224) ? (int)hwp[n] : -1;
  }

  // ---- P2/P3: X from xbb into xl; PV partials bf16 ----
  unsigned int ylo[2][16], yhi[2][16];
  #pragma unroll
  for (int half = 0; half < 2; ++half){
    __syncthreads();
    for (int i = tid; i < 128*32; i += 512){
      int c = i >> 5, m8 = i & 31;
      uint4 v = make_uint4(0u,0u,0u,0u);
      if (m8 < 30)
        v = *(const uint4*)(xbw + (size_t)(half*128 + c)*XBB_ROW + m8*8);
      *(uint4*)(&xl[swz(c, m8*8)]) = v;
    }
    __syncthreads();
    #pragma unroll
    for (int slot = 0; slot < 2; ++slot){
      const int nt = wave + slot*8;
      if (nt < 15){
        #pragma unroll
        for (int ct = 0; ct < 8; ++ct){
          f32x4 acc = {0.f,0.f,0.f,0.f};
          #pragma unroll
          for (int k = 0; k < 8; ++k){
            bf16x8 xf = ld_frag_lds(xl, swz(ct*16 + col, k*32 + hi*8));
            acc = MFMA(xf, __builtin_bit_cast(bf16x8, attf[slot][k]), acc);
          }
          ylo[slot][half*8 + ct] = (unsigned int)f2bf(acc[0]) | ((unsigned int)f2bf(acc[1]) << 16);
          yhi[slot][half*8 + ct] = (unsigned int)f2bf(acc[2]) | ((unsigned int)f2bf(acc[3]) << 16);
        }
      }
    }
  }

  uint4 y1f[2][8];
  #pragma unroll
  for (int slot = 0; slot < 2; ++slot){
    const int nt = wave + slot*8;
    if (nt < 15)
      repack_frag(ylo[slot], yhi[slot], y1f[slot], lane);
  }

  // ---- P4: projection from wpb, 4 rounds x 64 rows + bf16 residual ----
  #pragma unroll 1
  for (int oe2 = 0; oe2 < 4; ++oe2){
    __syncthreads();
    for (int i = tid; i < 64*32; i += 512){
      int olr = i >> 5, c8 = (i & 31)*8;
      *(uint4*)(&wl[swz(olr, c8)]) =
          *(const uint4*)(wpb + (size_t)(oe2*64 + olr)*256 + c8);
    }
    __syncthreads();
    #pragma unroll
    for (int ot = 0; ot < 4; ++ot){
      bf16x8 awf[8];
      const int olr = ot*16 + col;
      #pragma unroll
      for (int k = 0; k < 8; ++k)
        awf[k] = ld_frag_lds(wl, swz(olr, k*32 + hi*8));
      #pragma unroll
      for (int slot = 0; slot < 2; ++slot){
        const int nt = wave + slot*8;
        if (nt < 15){
          f32x4 y2 = {0.f,0.f,0.f,0.f};
          #pragma unroll
          for (int k = 0; k < 8; ++k)
            y2 = MFMA(awf[k], __builtin_bit_cast(bf16x8, y1f[slot][k]), y2);
          const int n = nt*16 + col;
          if (n <= 224){
            const size_t pix = (size_t)pixs[slot];
            #pragma unroll
            for (int jj = 0; jj < 4; ++jj){
              int o = oe2*64 + ot*16 + hi*4 + jj;
              float xr = bf2f(xbw[(size_t)o*XBB_ROW + n]);
              out[obase + (size_t)o*57600 + pix] = y2[jj] + xr;
            }
          }
        }
      }
    }
  }
}

// ---------------- small-ws fallback: R6-exact --------------------------------
__global__ __launch_bounds__(512) void k_qk(
    const float* __restrict__ x, const float* __restrict__ wq,
    const float* __restrict__ wk,
    unsigned short* __restrict__ qkws)
{
  __shared__ __align__(16) unsigned short S[32768];
  unsigned short* xt  = S;
  unsigned short* wqs = S;
  unsigned short* wks = S + 8192;
  const int wg  = blockIdx.x;
  const int b   = wg / 450;
  const int hw0 = (wg % 450) * 128;
  const int tid = threadIdx.x;
  const int lane = tid & 63, wave = tid >> 6;
  const int col  = lane & 15, hi = lane >> 4;

  {
    const float* xb = x + (size_t)b * 256 * 57600 + hw0;
    const int hw_l = tid & 127;
    #pragma unroll 4
    for (int i = 0; i < 32; ++i){
      int c = ((tid >> 7) * 32 + i) * 2;
      float f0 = xb[(size_t)c     * 57600 + hw_l];
      float f1 = xb[(size_t)(c+1) * 57600 + hw_l];
      *(unsigned int*)(&xt[swz(hw_l, c)]) =
          (unsigned int)f2bf(f0) | ((unsigned int)f2bf(f1) << 16);
    }
  }
  __syncthreads();

  bf16x8 af[8];
  const int arow = wave*16 + col;
  #pragma unroll
  for (int k = 0; k < 8; ++k)
    af[k] = ld_frag_lds(xt, swz(arow, k*32 + hi*8));

  const size_t orow_base = (size_t)b*57600 + hw0 + wave*16;

  for (int eg = 0; eg < 5; ++eg){
    __syncthreads();
    for (int i = 0; i < 8; ++i){
      int idx = tid + i*512;
      int e_l = idx >> 7, c = (idx & 127) * 2;
      int e = eg*32 + e_l;
      float2 vq = make_float2(0.f,0.f), vk = make_float2(0.f,0.f);
      if (e < 144){
        vq = *(const float2*)(wq + (size_t)e*256 + c);
        vk = *(const float2*)(wk + (size_t)e*256 + c);
      }
      *(unsigned int*)(&wqs[swz(e_l, c)]) =
          (unsigned int)f2bf(vq.x) | ((unsigned int)f2bf(vq.y) << 16);
      *(unsigned int*)(&wks[swz(e_l, c)]) =
          (unsigned int)f2bf(vk.x) | ((unsigned int)f2bf(vk.y) << 16);
    }
    __syncthreads();
    #pragma unroll
    for (int etl = 0; etl < 2; ++etl){
      f32x4 aq = {0.f,0.f,0.f,0.f}, ak = {0.f,0.f,0.f,0.f};
      const int el = etl*16 + col;
      #pragma unroll
      for (int k = 0; k < 8; ++k){
        int idx = swz(el, k*32 + hi*8);
        bf16x8 bq = ld_frag_lds(wqs, idx);
        bf16x8 bk = ld_frag_lds(wks, idx);
        aq = MFMA(af[k], bq, aq);
        ak = MFMA(af[k], bk, ak);
      }
      const int e_out = eg*32 + etl*16 + col;
      #pragma unroll
      for (int jj = 0; jj < 4; ++jj){
        size_t row = orow_base + hi*4 + jj;
        qkws[row*QK_ROW + e_out]       = f2bf(aq[jj]);
        qkws[row*QK_ROW + 160 + e_out] = f2bf(ak[jj]);
      }
    }
  }
}

__global__ __launch_bounds__(512,4) void k_attn_s(
    const float* __restrict__ x, const float* __restrict__ wproj,
    const unsigned short* __restrict__ qkws, float* __restrict__ out)
{
  __shared__ __align__(16) unsigned short S[40320 + 480];
  unsigned short* kl = S;
  unsigned short* xl = S;
  unsigned short* wl = S + 32768;
  unsigned int*  hwp = (unsigned int*)(S + 40320);
  const int wg = blockIdx.x;
  const int b  = wg >> 8;
  const int th = (wg >> 4) & 15, tw = wg & 15;
  const int h0 = th*15, w0 = tw*15;
  const int tid = threadIdx.x;
  const int lane = tid & 63, wave = tid >> 6;
  const int col  = lane & 15, hi = lane >> 4;
  const size_t xbase = (size_t)b * 256 * 57600;
  const unsigned short* qkb = qkws + (size_t)b * 57600 * QK_ROW;

  if (tid < 240){
    int ms = tid <= 224 ? tid : 224;
    hwp[tid] = (unsigned int)((h0 + ms/15)*240 + w0 + ms%15);
  }
  __syncthreads();

  for (int i = tid; i < 240*20; i += 512){
    int m = i / 20, eb = i - m*20;
    *(uint4*)(&kl[m*KL_STRIDE + eb*8]) =
        *(const uint4*)(qkb + (size_t)hwp[m]*QK_ROW + 160 + eb*8);
  }
  __syncthreads();

  uint4 attf[2][8];
  #pragma unroll
  for (int slot = 0; slot < 2; ++slot){
    const int nt = wave + slot*8;
    if (nt < 15){
      const int n  = nt*16 + col;
      const int na = n <= 224 ? n : 224;
      const unsigned short* qrow = qkb + (size_t)hwp[na]*QK_ROW;
      bf16x8 qf[5];
      #pragma unroll
      for (int c = 0; c < 5; ++c)
        qf[c] = ld_frag_b(qrow + c*32 + hi*8);
      f32x4 at[15];
      #pragma unroll
      for (int T = 0; T < 15; ++T){
        f32x4 acc = {0.f,0.f,0.f,0.f};
        #pragma unroll
        for (int c = 0; c < 5; ++c){
          bf16x8 kf = ld_frag_lds(kl, (T*16 + col)*KL_STRIDE + c*32 + hi*8);
          acc = MFMA(kf, qf[c], acc);
        }
        at[T] = acc;
      }
      const float sc = 0.12022458674074695f;
      float M = -3.0e38f;
      #pragma unroll
      for (int T = 0; T < 15; ++T){
        #pragma unroll
        for (int jj = 0; jj < 4; ++jj){
          int m = T*16 + hi*4 + jj;
          if (m <= 224) M = fmaxf(M, at[T][jj]*sc);
        }
      }
      M = fmaxf(M, __shfl_xor(M, 16));
      M = fmaxf(M, __shfl_xor(M, 32));
      float Ssum = 0.f;
      #pragma unroll
      for (int T = 0; T < 15; ++T){
        #pragma unroll
        for (int jj = 0; jj < 4; ++jj){
          int m = T*16 + hi*4 + jj;
          float v = (m <= 224) ? exp2f(at[T][jj]*sc - M) : 0.f;
          at[T][jj] = v; Ssum += v;
        }
      }
      Ssum += __shfl_xor(Ssum, 16);
      Ssum += __shfl_xor(Ssum, 32);
      const float inv = 1.0f / Ssum;
      unsigned int plo[16], phi[16];
      #pragma unroll
      for (int T = 0; T < 15; ++T){
        plo[T] = (unsigned int)f2bf(at[T][0]*inv) | ((unsigned int)f2bf(at[T][1]*inv) << 16);
        phi[T] = (unsigned int)f2bf(at[T][2]*inv) | ((unsigned int)f2bf(at[T][3]*inv) << 16);
      }
      plo[15] = 0u; phi[15] = 0u;
      repack_frag(plo, phi, attf[slot], lane);
    }
  }

  unsigned int ylo[2][16], yhi[2][16];
  #pragma unroll
  for (int half = 0; half < 2; ++half){
    __syncthreads();
    for (int i = tid; i < 128*128; i += 512){
      int c = i >> 7, m = (i & 127)*2;
      int m0 = m <= 224 ? m : 224;
      float f0 = (m     <= 224) ? x[xbase + (size_t)(half*128 + c)*57600 + hwp[m0]]   : 0.f;
      float f1 = (m + 1 <= 224) ? x[xbase + (size_t)(half*128 + c)*57600 + hwp[m0+1]] : 0.f;
      *(unsigned int*)(&xl[swz(c, m)]) =
          (unsigned int)f2bf(f0) | ((unsigned int)f2bf(f1) << 16);
    }
    __syncthreads();
    #pragma unroll
    for (int slot = 0; slot < 2; ++slot){
      const int nt = wave + slot*8;
      if (nt < 15){
        #pragma unroll
        for (int ct = 0; ct < 8; ++ct){
          f32x4 acc = {0.f,0.f,0.f,0.f};
          #pragma unroll
          for (int k = 0; k < 8; ++k){
            bf16x8 xf = ld_frag_lds(xl, swz(ct*16 + col, k*32 + hi*8));
            acc = MFMA(xf, __builtin_bit_cast(bf16x8, attf[slot][k]), acc);
          }
          ylo[slot][half*8 + ct] = (unsigned int)f2bf(acc[0]) | ((unsigned int)f2bf(acc[1]) << 16);
          yhi[slot][half*8 + ct] = (unsigned int)f2bf(acc[2]) | ((unsigned int)f2bf(acc[3]) << 16);
        }
      }
    }
  }

  uint4 y1f[2][8];
  #pragma unroll
  for (int slot = 0; slot < 2; ++slot){
    const int nt = wave + slot*8;
    if (nt < 15)
      repack_frag(ylo[slot], yhi[slot], y1f[slot], lane);
  }

  #pragma unroll 1
  for (int oe = 0; oe < 16; ++oe){
    __syncthreads();
    for (int i = tid; i < 16*128; i += 512){
      int olr = i >> 7, c = (i & 127)*2;
      const float* wr = wproj + (size_t)(oe*16 + olr)*256 + c;
      *(unsigned int*)(&wl[swz(olr, c)]) =
          (unsigned int)f2bf(wr[0]) | ((unsigned int)f2bf(wr[1]) << 16);
    }
    __syncthreads();
    bf16x8 awf[8];
    #pragma unroll
    for (int k = 0; k < 8; ++k)
      awf[k] = ld_frag_lds(wl, swz(col, k*32 + hi*8));
    #pragma unroll
    for (int slot = 0; slot < 2; ++slot){
      const int nt = wave + slot*8;
      if (nt < 15){
        f32x4 y2 = {0.f,0.f,0.f,0.f};
        #pragma unroll
        for (int k = 0; k < 8; ++k)
          y2 = MFMA(awf[k], __builtin_bit_cast(bf16x8, y1f[slot][k]), y2);
        const int n = nt*16 + col;
        if (n <= 224){
          const size_t pix = hwp[n];
          #pragma unroll
          for (int jj = 0; jj < 4; ++jj){
            int o = oe*16 + hi*4 + jj;
            const size_t idx = xbase + (size_t)o*57600 + pix;
            out[idx] = y2[jj] + x[idx];
          }
        }
      }
    }
  }
}

extern "C" void kernel_launch(void* const* d_in, const int* in_sizes, int n_in,
                              void* d_out, int out_size, void* d_ws, size_t ws_size,
                              hipStream_t stream)
{
  const float* x     = (const float*)d_in[0];
  const float* wq    = (const float*)d_in[1];
  const float* wk    = (const float*)d_in[2];
  const float* wproj = (const float*)d_in[3];
  float* out = (float*)d_out;
  (void)in_sizes; (void)n_in; (void)out_size;

  const size_t QKWS_B = (size_t)8*57600*QK_ROW*2;        // 294,912,000
  const size_t XBB_B  = (size_t)8*256*256*XBB_ROW*2;     // 251,658,240
  const size_t WB_ALL = (size_t)(160*256 + 160*256 + 256*256)*2;  // 294,912
  unsigned short* qkws = (unsigned short*)d_ws;

  if (ws_size >= QKWS_B + XBB_B + WB_ALL){                // confirmed fits (R10/R12)
    unsigned short* xbb = (unsigned short*)((char*)d_ws + QKWS_B);
    unsigned short* wqb = (unsigned short*)((char*)d_ws + QKWS_B + XBB_B);
    unsigned short* wkb = wqb + 160*256;
    unsigned short* wpb = wkb + 160*256;
    k_w    <<<dim3(288),  dim3(256), 0, stream>>>(wq, wk, wproj, wqb, wkb, wpb);
    k_xb   <<<dim3(4096), dim3(256), 0, stream>>>(x, xbb);
    k_fused<<<dim3(2048), dim3(512), 0, stream>>>(xbb, wqb, wkb, wpb, qkws, out);
  } else {
    k_qk    <<<dim3(3600), dim3(512), 0, stream>>>(x, wq, wk, qkws);
    k_attn_s<<<dim3(2048), dim3(512), 0, stream>>>(x, wproj, qkws, out);
  }
}

// Round 17
// 944.887 us; speedup vs baseline: 1.2273x; 1.0251x over previous
//
#include <hip/hip_runtime.h>

// PNLM: patch (15x15) non-local attention + projection + residual.
// R17 == R12 verbatim (session best: 946 us, absmax 0.03125).
// k_w    : bf16 weight copies (wqb/wkb zero-padded [160][256], wpb[256][256]).
// k_xb   : x (raster fp32) -> xbb[blk][c][240] bf16 (proven).
// k_fused: per block: phase A = QK projection (xbb -> xt halves -> af[2][8],
//          5-eg LDS-staged weights, direct qkws stores); barrier; phase B =
//          attention (P0 kl L2-hot, P1 att^T + lane-local softmax, PV from
//          xbb halves, P4 proj from wpb in 4x64-row rounds, bf16 residual).
// k_qk / k_attn_s: small-ws fallback (R6-exact, proven).
// NO v_cvt_pk_bf16_f32 inline asm (NaN, R2/R3/R5).
// NO fragment-granularity global reads in phase A (TA-scatter, R4/R13).
// NO large register sets held across phase A (spills, R8/R15).

typedef __bf16 bf16x8 __attribute__((ext_vector_type(8)));
typedef float  f32x4  __attribute__((ext_vector_type(4)));

#define MFMA(a,b,c) __builtin_amdgcn_mfma_f32_16x16x32_bf16((a),(b),(c),0,0,0)

#define QK_ROW 320            // Q cols 0..159 (144+ zero), K cols 160..319 (144+ zero)
#define KL_STRIDE 168         // kl row stride in ushorts (336B, 16B-aligned)
#define XBB_ROW 240           // xbb row length in ushorts (480B)

__device__ __forceinline__ unsigned short f2bf(float f){
  union { float f; unsigned int u; } v; v.f = f;
  unsigned int r = v.u + 0x7FFFu + ((v.u >> 16) & 1u);   // RNE
  return (unsigned short)(r >> 16);
}
__device__ __forceinline__ float bf2f(unsigned short u){
  union { unsigned int u; float f; } v; v.u = ((unsigned int)u) << 16;
  return v.f;
}
__device__ __forceinline__ int swz(int row, int col){
  return row*256 + ((((col >> 3) ^ (row & 7)) << 3) | (col & 7));
}
__device__ __forceinline__ int swzC(int row, int col){
  return row*256 + (col ^ ((((row >> 3) ^ row) & 7) << 3));
}
__device__ __forceinline__ bf16x8 ld_frag_lds(const unsigned short* p, int idx){
  uint4 v = *(const uint4*)(p + idx);
  return __builtin_bit_cast(bf16x8, v);
}
__device__ __forceinline__ bf16x8 ld_frag_b(const void* p){
  uint4 v = *(const uint4*)(p);
  return __builtin_bit_cast(bf16x8, v);
}

__device__ __forceinline__ void repack_frag(const unsigned int* plo, const unsigned int* phi,
                                            uint4* outf, int lane){
  const int nn = lane & 15, hh = lane >> 4;
  const int sla = nn + 32*(hh & 1);
  const int slb = sla + 16;
  const bool up = hh >= 2;
  #pragma unroll
  for (int k = 0; k < 8; ++k){
    unsigned int a0 = (unsigned int)__shfl((int)plo[2*k],   sla);
    unsigned int a1 = (unsigned int)__shfl((int)plo[2*k+1], sla);
    unsigned int b0 = (unsigned int)__shfl((int)phi[2*k],   sla);
    unsigned int b1 = (unsigned int)__shfl((int)phi[2*k+1], sla);
    unsigned int c0 = (unsigned int)__shfl((int)plo[2*k],   slb);
    unsigned int c1 = (unsigned int)__shfl((int)plo[2*k+1], slb);
    unsigned int d0 = (unsigned int)__shfl((int)phi[2*k],   slb);
    unsigned int d1 = (unsigned int)__shfl((int)phi[2*k+1], slb);
    outf[k] = make_uint4(up?a1:a0, up?b1:b0, up?c1:c0, up?d1:d0);
  }
}

// ---------------- kernel W: bf16 weight copies -------------------------------
__global__ __launch_bounds__(256) void k_w(
    const float* __restrict__ wq, const float* __restrict__ wk,
    const float* __restrict__ wproj,
    unsigned short* __restrict__ wqb, unsigned short* __restrict__ wkb,
    unsigned short* __restrict__ wpb)
{
  int i = blockIdx.x*256 + threadIdx.x;             // pair index, grid 288
  if (i < 20480){
    int e = i >> 7, c = (i & 127)*2;
    unsigned int v = 0;
    if (e < 144) v = (unsigned int)f2bf(wq[e*256+c]) | ((unsigned int)f2bf(wq[e*256+c+1]) << 16);
    *(unsigned int*)(wqb + (size_t)i*2) = v;
  } else if (i < 40960){
    int j = i - 20480;
    int e = j >> 7, c = (j & 127)*2;
    unsigned int v = 0;
    if (e < 144) v = (unsigned int)f2bf(wk[e*256+c]) | ((unsigned int)f2bf(wk[e*256+c+1]) << 16);
    *(unsigned int*)(wkb + (size_t)j*2) = v;
  } else if (i < 73728){
    int l = i - 40960;
    int o = l >> 7, c = (l & 127)*2;
    *(unsigned int*)(wpb + (size_t)l*2) =
        (unsigned int)f2bf(wproj[o*256+c]) | ((unsigned int)f2bf(wproj[o*256+c+1]) << 16);
  }
}

// ---------------- kernel 0: x -> xbb blocked transpose (frozen) --------------
__global__ __launch_bounds__(256) void k_xb(
    const float* __restrict__ x, unsigned short* __restrict__ xbb)
{
  __shared__ unsigned short xs[8*15*240];
  const int wg = blockIdx.x;                // b(8) x th(16) x cg(32)
  const int cg = wg & 31;
  const int th = (wg >> 5) & 15;
  const int b  = wg >> 9;
  const int tid = threadIdx.x;

  const float* xb = x + ((size_t)b*256 + cg*8)*57600 + th*15*240;
  for (int i = tid; i < 8*15*120; i += 256){
    int c = i / 1800;
    int rem = i - c*1800;
    int r = rem / 120, p2 = rem - r*120;
    float2 v = *(const float2*)(xb + (size_t)c*57600 + r*240 + p2*2);
    *(unsigned int*)(&xs[(c*15 + r)*240 + p2*2]) =
        (unsigned int)f2bf(v.x) | ((unsigned int)f2bf(v.y) << 16);
  }
  __syncthreads();

  for (int i = tid; i < 8*16*30; i += 256){
    int c = i / 480;
    int rem = i - c*480;
    int tw = rem / 30, ch = rem - tw*30;
    union { unsigned short u16[8]; uint4 u4; } pk;
    #pragma unroll
    for (int j = 0; j < 8; ++j){
      int m = ch*8 + j;
      int r = m / 15, s = m - r*15;
      pk.u16[j] = (m <= 224) ? xs[(c*15 + r)*240 + tw*15 + s] : (unsigned short)0;
    }
    *(uint4*)(xbb + ((size_t)(b*256 + th*16 + tw)*256 + cg*8 + c)*XBB_ROW + ch*8) = pk.u4;
  }
}

// ---------------- fused kernel: QK projection + attention --------------------
__global__ __launch_bounds__(512,4) void k_fused(
    const unsigned short* __restrict__ xbb,
    const unsigned short* __restrict__ wqb, const unsigned short* __restrict__ wkb,
    const unsigned short* __restrict__ wpb,
    unsigned short* __restrict__ qkws, float* __restrict__ out)
{
  // LDS union (81,920B -> 2 WG/CU):
  //   phase A: xt[128][256] swzC (0..32,768 ush); wqs/wks alias xt after af.
  //   phase B: kl[240][168] (0..40,320) | xl[128][256] (0..32,768)
  //            | wl[64][256] (0..16,384, after xl dead) | hwp (40,320..40,800)
  __shared__ __align__(16) unsigned short S[40960];
  unsigned short* xt  = S;
  unsigned short* wqs = S;
  unsigned short* wks = S + 8192;
  unsigned short* kl  = S;
  unsigned short* xl  = S;
  unsigned short* wl  = S;
  unsigned int*  hwp  = (unsigned int*)(S + 40320);
  const int wg = blockIdx.x;
  const int b  = wg >> 8;
  const int th = (wg >> 4) & 15, tw = wg & 15;
  const int h0 = th*15, w0 = tw*15;
  const int tid = threadIdx.x;
  const int lane = tid & 63, wave = tid >> 6;
  const int col  = lane & 15, hi = lane >> 4;
  const size_t obase = (size_t)b * 256 * 57600;
  const unsigned short* qkb = qkws + (size_t)b * 57600 * QK_ROW;
  const unsigned short* xbw = xbb + (size_t)wg * (256*XBB_ROW);

  if (tid < 240){                               // hwp region untouched by phase A
    int ms = tid <= 224 ? tid : 224;
    hwp[tid] = (unsigned int)((h0 + ms/15)*240 + w0 + ms%15);
  }

  // ================= phase A: QK projection ==================================
  bf16x8 af[2][8];
  #pragma unroll 1
  for (int half = 0; half < 2; ++half){
    if (half) __syncthreads();
    for (int i = tid; i < 256*16; i += 512){
      int c = i >> 4, m8 = i & 15;
      int m = half*128 + m8*8;
      if (m + 8 <= 240){
        uint4 v = *(const uint4*)(xbw + (size_t)c*XBB_ROW + m);
        const unsigned short* pv = (const unsigned short*)&v;
        #pragma unroll
        for (int j = 0; j < 8; ++j)
          xt[swzC(m8*8 + j, c)] = pv[j];
      }
    }
    __syncthreads();
    const int rloc = wave*16 + col;
    if (half == 0){
      #pragma unroll
      for (int k = 0; k < 8; ++k)
        af[0][k] = ld_frag_lds(xt, swzC(rloc, k*32 + hi*8));
    } else {
      #pragma unroll
      for (int k = 0; k < 8; ++k)
        af[1][k] = ld_frag_lds(xt, swzC(rloc, k*32 + hi*8));
    }
  }
  __syncthreads();                             // xt consumed -> weights

  #pragma unroll 1
  for (int eg = 0; eg < 5; ++eg){
    if (eg) __syncthreads();
    for (int i = tid; i < 32*32; i += 512){
      int e_l = i >> 5, c8 = (i & 31)*8;
      size_t off = (size_t)(eg*32 + e_l)*256 + c8;
      *(uint4*)(&wqs[swz(e_l, c8)]) = *(const uint4*)(wqb + off);
      *(uint4*)(&wks[swz(e_l, c8)]) = *(const uint4*)(wkb + off);
    }
    __syncthreads();
    #pragma unroll
    for (int h2 = 0; h2 < 2; ++h2){
      const int t = h2*8 + wave;
      if (t < 15){
        #pragma unroll
        for (int et = 0; et < 2; ++et){
          f32x4 aq = {0.f,0.f,0.f,0.f}, ak = {0.f,0.f,0.f,0.f};
          const int el = et*16 + col;
          #pragma unroll
          for (int k = 0; k < 8; ++k){
            int idx = swz(el, k*32 + hi*8);
            bf16x8 bq = ld_frag_lds(wqs, idx);
            bf16x8 bk = ld_frag_lds(wks, idx);
            aq = MFMA(af[h2][k], bq, aq);
            ak = MFMA(af[h2][k], bk, ak);
          }
          const int e_out = eg*32 + et*16 + col;
          #pragma unroll
          for (int jj = 0; jj < 4; ++jj){
            int m_px = t*16 + hi*4 + jj;
            if (m_px <= 224){
              int hw = (h0 + m_px/15)*240 + w0 + m_px%15;
              size_t row = ((size_t)b*57600 + hw)*QK_ROW;
              qkws[row + e_out]       = f2bf(aq[jj]);
              qkws[row + 160 + e_out] = f2bf(ak[jj]);
            }
          }
        }
      }
    }
  }
  __syncthreads();   // phase boundary: drains qkws stores; wqs/wks dead

  // ================= phase B: attention ======================================
  // ---- P0: stage K rows into kl (L2-hot reads of own block's rows) ----
  for (int i = tid; i < 240*20; i += 512){
    int m = i / 20, eb = i - m*20;
    *(uint4*)(&kl[m*KL_STRIDE + eb*8]) =
        *(const uint4*)(qkb + (size_t)hwp[m]*QK_ROW + 160 + eb*8);
  }
  __syncthreads();

  // ---- P1: att^T strips + lane-local softmax + register repack ----
  uint4 attf[2][8];
  #pragma unroll
  for (int slot = 0; slot < 2; ++slot){
    const int nt = wave + slot*8;
    if (nt < 15){
      const int n  = nt*16 + col;
      const int na = n <= 224 ? n : 224;
      const unsigned short* qrow = qkb + (size_t)hwp[na]*QK_ROW;
      bf16x8 qf[5];
      #pragma unroll
      for (int c = 0; c < 5; ++c)
        qf[c] = ld_frag_b(qrow + c*32 + hi*8);
      f32x4 at[15];
      #pragma unroll
      for (int T = 0; T < 15; ++T){
        f32x4 acc = {0.f,0.f,0.f,0.f};
        #pragma unroll
        for (int c = 0; c < 5; ++c){
          bf16x8 kf = ld_frag_lds(kl, (T*16 + col)*KL_STRIDE + c*32 + hi*8);
          acc = MFMA(kf, qf[c], acc);             // att^T[m][n]
        }
        at[T] = acc;
      }
      const float sc = 0.12022458674074695f;      // log2(e)/12
      float M = -3.0e38f;
      #pragma unroll
      for (int T = 0; T < 15; ++T){
        #pragma unroll
        for (int jj = 0; jj < 4; ++jj){
          int m = T*16 + hi*4 + jj;
          if (m <= 224) M = fmaxf(M, at[T][jj]*sc);
        }
      }
      M = fmaxf(M, __shfl_xor(M, 16));
      M = fmaxf(M, __shfl_xor(M, 32));
      float Ssum = 0.f;
      #pragma unroll
      for (int T = 0; T < 15; ++T){
        #pragma unroll
        for (int jj = 0; jj < 4; ++jj){
          int m = T*16 + hi*4 + jj;
          float v = (m <= 224) ? exp2f(at[T][jj]*sc - M) : 0.f;
          at[T][jj] = v; Ssum += v;
        }
      }
      Ssum += __shfl_xor(Ssum, 16);
      Ssum += __shfl_xor(Ssum, 32);
      const float inv = 1.0f / Ssum;
      unsigned int plo[16], phi[16];
      #pragma unroll
      for (int T = 0; T < 15; ++T){
        plo[T] = (unsigned int)f2bf(at[T][0]*inv) | ((unsigned int)f2bf(at[T][1]*inv) << 16);
        phi[T] = (unsigned int)f2bf(at[T][2]*inv) | ((unsigned int)f2bf(at[T][3]*inv) << 16);
      }
      plo[15] = 0u; phi[15] = 0u;
      repack_frag(plo, phi, attf[slot], lane);
    }
  }

  // hoist per-slot store coords
  int pixs[2];
  #pragma unroll
  for (int slot = 0; slot < 2; ++slot){
    const int n = (wave + slot*8)*16 + col;
    pixs[slot] = (n <= 224) ? (int)hwp[n] : -1;
  }

  // ---- P2/P3: X from xbb into xl; PV partials bf16 ----
  unsigned int ylo[2][16], yhi[2][16];
  #pragma unroll
  for (int half = 0; half < 2; ++half){
    __syncthreads();
    for (int i = tid; i < 128*32; i += 512){
      int c = i >> 5, m8 = i & 31;
      uint4 v = make_uint4(0u,0u,0u,0u);
      if (m8 < 30)
        v = *(const uint4*)(xbw + (size_t)(half*128 + c)*XBB_ROW + m8*8);
      *(uint4*)(&xl[swz(c, m8*8)]) = v;
    }
    __syncthreads();
    #pragma unroll
    for (int slot = 0; slot < 2; ++slot){
      const int nt = wave + slot*8;
      if (nt < 15){
        #pragma unroll
        for (int ct = 0; ct < 8; ++ct){
          f32x4 acc = {0.f,0.f,0.f,0.f};
          #pragma unroll
          for (int k = 0; k < 8; ++k){
            bf16x8 xf = ld_frag_lds(xl, swz(ct*16 + col, k*32 + hi*8));
            acc = MFMA(xf, __builtin_bit_cast(bf16x8, attf[slot][k]), acc);
          }
          ylo[slot][half*8 + ct] = (unsigned int)f2bf(acc[0]) | ((unsigned int)f2bf(acc[1]) << 16);
          yhi[slot][half*8 + ct] = (unsigned int)f2bf(acc[2]) | ((unsigned int)f2bf(acc[3]) << 16);
        }
      }
    }
  }

  uint4 y1f[2][8];
  #pragma unroll
  for (int slot = 0; slot < 2; ++slot){
    const int nt = wave + slot*8;
    if (nt < 15)
      repack_frag(ylo[slot], yhi[slot], y1f[slot], lane);
  }

  // ---- P4: projection from wpb, 4 rounds x 64 rows + bf16 residual ----
  #pragma unroll 1
  for (int oe2 = 0; oe2 < 4; ++oe2){
    __syncthreads();                          // PV readers / prev wl readers done
    for (int i = tid; i < 64*32; i += 512){
      int olr = i >> 5, c8 = (i & 31)*8;
      *(uint4*)(&wl[swz(olr, c8)]) =
          *(const uint4*)(wpb + (size_t)(oe2*64 + olr)*256 + c8);
    }
    __syncthreads();
    #pragma unroll
    for (int ot = 0; ot < 4; ++ot){
      bf16x8 awf[8];
      const int olr = ot*16 + col;
      #pragma unroll
      for (int k = 0; k < 8; ++k)
        awf[k] = ld_frag_lds(wl, swz(olr, k*32 + hi*8));
      #pragma unroll
      for (int slot = 0; slot < 2; ++slot){
        const int nt = wave + slot*8;
        if (nt < 15){
          f32x4 y2 = {0.f,0.f,0.f,0.f};
          #pragma unroll
          for (int k = 0; k < 8; ++k)
            y2 = MFMA(awf[k], __builtin_bit_cast(bf16x8, y1f[slot][k]), y2);
          const int n = nt*16 + col;
          if (n <= 224){
            const size_t pix = (size_t)pixs[slot];
            #pragma unroll
            for (int jj = 0; jj < 4; ++jj){
              int o = oe2*64 + ot*16 + hi*4 + jj;
              float xr = bf2f(xbw[(size_t)o*XBB_ROW + n]);
              out[obase + (size_t)o*57600 + pix] = y2[jj] + xr;
            }
          }
        }
      }
    }
  }
}

// ---------------- small-ws fallback: R6-exact --------------------------------
__global__ __launch_bounds__(512) void k_qk(
    const float* __restrict__ x, const float* __restrict__ wq,
    const float* __restrict__ wk,
    unsigned short* __restrict__ qkws)
{
  __shared__ __align__(16) unsigned short S[32768];
  unsigned short* xt  = S;
  unsigned short* wqs = S;
  unsigned short* wks = S + 8192;
  const int wg  = blockIdx.x;
  const int b   = wg / 450;
  const int hw0 = (wg % 450) * 128;
  const int tid = threadIdx.x;
  const int lane = tid & 63, wave = tid >> 6;
  const int col  = lane & 15, hi = lane >> 4;

  {
    const float* xb = x + (size_t)b * 256 * 57600 + hw0;
    const int hw_l = tid & 127;
    #pragma unroll 4
    for (int i = 0; i < 32; ++i){
      int c = ((tid >> 7) * 32 + i) * 2;
      float f0 = xb[(size_t)c     * 57600 + hw_l];
      float f1 = xb[(size_t)(c+1) * 57600 + hw_l];
      *(unsigned int*)(&xt[swz(hw_l, c)]) =
          (unsigned int)f2bf(f0) | ((unsigned int)f2bf(f1) << 16);
    }
  }
  __syncthreads();

  bf16x8 af[8];
  const int arow = wave*16 + col;
  #pragma unroll
  for (int k = 0; k < 8; ++k)
    af[k] = ld_frag_lds(xt, swz(arow, k*32 + hi*8));

  const size_t orow_base = (size_t)b*57600 + hw0 + wave*16;

  for (int eg = 0; eg < 5; ++eg){
    __syncthreads();
    for (int i = 0; i < 8; ++i){
      int idx = tid + i*512;
      int e_l = idx >> 7, c = (idx & 127) * 2;
      int e = eg*32 + e_l;
      float2 vq = make_float2(0.f,0.f), vk = make_float2(0.f,0.f);
      if (e < 144){
        vq = *(const float2*)(wq + (size_t)e*256 + c);
        vk = *(const float2*)(wk + (size_t)e*256 + c);
      }
      *(unsigned int*)(&wqs[swz(e_l, c)]) =
          (unsigned int)f2bf(vq.x) | ((unsigned int)f2bf(vq.y) << 16);
      *(unsigned int*)(&wks[swz(e_l, c)]) =
          (unsigned int)f2bf(vk.x) | ((unsigned int)f2bf(vk.y) << 16);
    }
    __syncthreads();
    #pragma unroll
    for (int etl = 0; etl < 2; ++etl){
      f32x4 aq = {0.f,0.f,0.f,0.f}, ak = {0.f,0.f,0.f,0.f};
      const int el = etl*16 + col;
      #pragma unroll
      for (int k = 0; k < 8; ++k){
        int idx = swz(el, k*32 + hi*8);
        bf16x8 bq = ld_frag_lds(wqs, idx);
        bf16x8 bk = ld_frag_lds(wks, idx);
        aq = MFMA(af[k], bq, aq);
        ak = MFMA(af[k], bk, ak);
      }
      const int e_out = eg*32 + etl*16 + col;
      #pragma unroll
      for (int jj = 0; jj < 4; ++jj){
        size_t row = orow_base + hi*4 + jj;
        qkws[row*QK_ROW + e_out]       = f2bf(aq[jj]);
        qkws[row*QK_ROW + 160 + e_out] = f2bf(ak[jj]);
      }
    }
  }
}

__global__ __launch_bounds__(512,4) void k_attn_s(
    const float* __restrict__ x, const float* __restrict__ wproj,
    const unsigned short* __restrict__ qkws, float* __restrict__ out)
{
  __shared__ __align__(16) unsigned short S[40320 + 480];
  unsigned short* kl = S;
  unsigned short* xl = S;
  unsigned short* wl = S + 32768;
  unsigned int*  hwp = (unsigned int*)(S + 40320);
  const int wg = blockIdx.x;
  const int b  = wg >> 8;
  const int th = (wg >> 4) & 15, tw = wg & 15;
  const int h0 = th*15, w0 = tw*15;
  const int tid = threadIdx.x;
  const int lane = tid & 63, wave = tid >> 6;
  const int col  = lane & 15, hi = lane >> 4;
  const size_t xbase = (size_t)b * 256 * 57600;
  const unsigned short* qkb = qkws + (size_t)b * 57600 * QK_ROW;

  if (tid < 240){
    int ms = tid <= 224 ? tid : 224;
    hwp[tid] = (unsigned int)((h0 + ms/15)*240 + w0 + ms%15);
  }
  __syncthreads();

  for (int i = tid; i < 240*20; i += 512){
    int m = i / 20, eb = i - m*20;
    *(uint4*)(&kl[m*KL_STRIDE + eb*8]) =
        *(const uint4*)(qkb + (size_t)hwp[m]*QK_ROW + 160 + eb*8);
  }
  __syncthreads();

  uint4 attf[2][8];
  #pragma unroll
  for (int slot = 0; slot < 2; ++slot){
    const int nt = wave + slot*8;
    if (nt < 15){
      const int n  = nt*16 + col;
      const int na = n <= 224 ? n : 224;
      const unsigned short* qrow = qkb + (size_t)hwp[na]*QK_ROW;
      bf16x8 qf[5];
      #pragma unroll
      for (int c = 0; c < 5; ++c)
        qf[c] = ld_frag_b(qrow + c*32 + hi*8);
      f32x4 at[15];
      #pragma unroll
      for (int T = 0; T < 15; ++T){
        f32x4 acc = {0.f,0.f,0.f,0.f};
        #pragma unroll
        for (int c = 0; c < 5; ++c){
          bf16x8 kf = ld_frag_lds(kl, (T*16 + col)*KL_STRIDE + c*32 + hi*8);
          acc = MFMA(kf, qf[c], acc);
        }
        at[T] = acc;
      }
      const float sc = 0.12022458674074695f;
      float M = -3.0e38f;
      #pragma unroll
      for (int T = 0; T < 15; ++T){
        #pragma unroll
        for (int jj = 0; jj < 4; ++jj){
          int m = T*16 + hi*4 + jj;
          if (m <= 224) M = fmaxf(M, at[T][jj]*sc);
        }
      }
      M = fmaxf(M, __shfl_xor(M, 16));
      M = fmaxf(M, __shfl_xor(M, 32));
      float Ssum = 0.f;
      #pragma unroll
      for (int T = 0; T < 15; ++T){
        #pragma unroll
        for (int jj = 0; jj < 4; ++jj){
          int m = T*16 + hi*4 + jj;
          float v = (m <= 224) ? exp2f(at[T][jj]*sc - M) : 0.f;
          at[T][jj] = v; Ssum += v;
        }
      }
      Ssum += __shfl_xor(Ssum, 16);
      Ssum += __shfl_xor(Ssum, 32);
      const float inv = 1.0f / Ssum;
      unsigned int plo[16], phi[16];
      #pragma unroll
      for (int T = 0; T < 15; ++T){
        plo[T] = (unsigned int)f2bf(at[T][0]*inv) | ((unsigned int)f2bf(at[T][1]*inv) << 16);
        phi[T] = (unsigned int)f2bf(at[T][2]*inv) | ((unsigned int)f2bf(at[T][3]*inv) << 16);
      }
      plo[15] = 0u; phi[15] = 0u;
      repack_frag(plo, phi, attf[slot], lane);
    }
  }

  unsigned int ylo[2][16], yhi[2][16];
  #pragma unroll
  for (int half = 0; half < 2; ++half){
    __syncthreads();
    for (int i = tid; i < 128*128; i += 512){
      int c = i >> 7, m = (i & 127)*2;
      int m0 = m <= 224 ? m : 224;
      float f0 = (m     <= 224) ? x[xbase + (size_t)(half*128 + c)*57600 + hwp[m0]]   : 0.f;
      float f1 = (m + 1 <= 224) ? x[xbase + (size_t)(half*128 + c)*57600 + hwp[m0+1]] : 0.f;
      *(unsigned int*)(&xl[swz(c, m)]) =
          (unsigned int)f2bf(f0) | ((unsigned int)f2bf(f1) << 16);
    }
    __syncthreads();
    #pragma unroll
    for (int slot = 0; slot < 2; ++slot){
      const int nt = wave + slot*8;
      if (nt < 15){
        #pragma unroll
        for (int ct = 0; ct < 8; ++ct){
          f32x4 acc = {0.f,0.f,0.f,0.f};
          #pragma unroll
          for (int k = 0; k < 8; ++k){
            bf16x8 xf = ld_frag_lds(xl, swz(ct*16 + col, k*32 + hi*8));
            acc = MFMA(xf, __builtin_bit_cast(bf16x8, attf[slot][k]), acc);
          }
          ylo[slot][half*8 + ct] = (unsigned int)f2bf(acc[0]) | ((unsigned int)f2bf(acc[1]) << 16);
          yhi[slot][half*8 + ct] = (unsigned int)f2bf(acc[2]) | ((unsigned int)f2bf(acc[3]) << 16);
        }
      }
    }
  }

  uint4 y1f[2][8];
  #pragma unroll
  for (int slot = 0; slot < 2; ++slot){
    const int nt = wave + slot*8;
    if (nt < 15)
      repack_frag(ylo[slot], yhi[slot], y1f[slot], lane);
  }

  #pragma unroll 1
  for (int oe = 0; oe < 16; ++oe){
    __syncthreads();
    for (int i = tid; i < 16*128; i += 512){
      int olr = i >> 7, c = (i & 127)*2;
      const float* wr = wproj + (size_t)(oe*16 + olr)*256 + c;
      *(unsigned int*)(&wl[swz(olr, c)]) =
          (unsigned int)f2bf(wr[0]) | ((unsigned int)f2bf(wr[1]) << 16);
    }
    __syncthreads();
    bf16x8 awf[8];
    #pragma unroll
    for (int k = 0; k < 8; ++k)
      awf[k] = ld_frag_lds(wl, swz(col, k*32 + hi*8));
    #pragma unroll
    for (int slot = 0; slot < 2; ++slot){
      const int nt = wave + slot*8;
      if (nt < 15){
        f32x4 y2 = {0.f,0.f,0.f,0.f};
        #pragma unroll
        for (int k = 0; k < 8; ++k)
          y2 = MFMA(awf[k], __builtin_bit_cast(bf16x8, y1f[slot][k]), y2);
        const int n = nt*16 + col;
        if (n <= 224){
          const size_t pix = hwp[n];
          #pragma unroll
          for (int jj = 0; jj < 4; ++jj){
            int o = oe*16 + hi*4 + jj;
            const size_t idx = xbase + (size_t)o*57600 + pix;
            out[idx] = y2[jj] + x[idx];
          }
        }
      }
    }
  }
}

extern "C" void kernel_launch(void* const* d_in, const int* in_sizes, int n_in,
                              void* d_out, int out_size, void* d_ws, size_t ws_size,
                              hipStream_t stream)
{
  const float* x     = (const float*)d_in[0];
  const float* wq    = (const float*)d_in[1];
  const float* wk    = (const float*)d_in[2];
  const float* wproj = (const float*)d_in[3];
  float* out = (float*)d_out;
  (void)in_sizes; (void)n_in; (void)out_size;

  const size_t QKWS_B = (size_t)8*57600*QK_ROW*2;        // 294,912,000
  const size_t XBB_B  = (size_t)8*256*256*XBB_ROW*2;     // 251,658,240
  const size_t WB_ALL = (size_t)(160*256 + 160*256 + 256*256)*2;  // 294,912
  unsigned short* qkws = (unsigned short*)d_ws;

  if (ws_size >= QKWS_B + XBB_B + WB_ALL){                // confirmed fits (R10/R12)
    unsigned short* xbb = (unsigned short*)((char*)d_ws + QKWS_B);
    unsigned short* wqb = (unsigned short*)((char*)d_ws + QKWS_B + XBB_B);
    unsigned short* wkb = wqb + 160*256;
    unsigned short* wpb = wkb + 160*256;
    k_w    <<<dim3(288),  dim3(256), 0, stream>>>(wq, wk, wproj, wqb, wkb, wpb);
    k_xb   <<<dim3(4096), dim3(256), 0, stream>>>(x, xbb);
    k_fused<<<dim3(2048), dim3(512), 0, stream>>>(xbb, wqb, wkb, wpb, qkws, out);
  } else {
    k_qk    <<<dim3(3600), dim3(512), 0, stream>>>(x, wq, wk, qkws);
    k_attn_s<<<dim3(2048), dim3(512), 0, stream>>>(x, wproj, qkws, out);
  }
}